// Round 5
// baseline (253.884 us; speedup 1.0000x reference)
//
#include <hip/hip_runtime.h>
#include <math.h>

// f32 FFT pipeline, genuinely spill-free this time.
// Evidence from rounds 2-4: the 160-float energy stash spills under ANY
// register cap below ~230 (launch_bounds(256,2) -> cap 128 -> 68 MB scratch;
// waves_per_eu(3,8) -> compiler chose 84 VGPR -> 131 MB scratch). The only
// proven no-spill config is launch_bounds(256,1) (round 2: VGPR=220,
// WRITE_SIZE=192 KB). So: full f32 stash + cap 512. LDS 54272 B -> 2
// blocks/CU; VGPR ~230 -> 2 waves/EU -> 8 waves/CU, consistent.

#define NTH 256
#define PHYS(i) ((i) + ((i) >> 4))

// ---------------- fused setup: transpose + tables ----------------
__device__ __forceinline__ float mask_f32(int k, int j) {
  // replicate reference: freqs=fftfreq(4096).astype(f32), centers f32, /0.2f, expf
  float f = (float)((j < 2048) ? j : (j - 4096)) * (1.0f / 4096.0f);
  float c = ((float)k - 2.5f) / 5.0f;
  float df = fabsf(f - c);
  float q = df / 0.2f;
  return expf(-0.5f * (q * q));
}

__global__ void setup_k(const float* __restrict__ x, float* __restrict__ xT,
                        float2* __restrict__ Wt, float* __restrict__ Mdr, int n_trans) {
  __shared__ float tile[64][65];
  if ((int)blockIdx.x < n_trans) {
    int bb = blockIdx.x >> 6;
    int tt = blockIdx.x & 63;
    int lane = threadIdx.x & 63;
    int grp = threadIdx.x >> 6;
#pragma unroll
    for (int r = 0; r < 16; ++r) {
      int tl = grp + 4 * r;
      tile[tl][lane] = x[((size_t)bb * 4096 + tt * 64 + tl) * 64 + lane];
    }
    __syncthreads();
#pragma unroll
    for (int r = 0; r < 16; ++r) {
      int dl = grp + 4 * r;
      xT[((size_t)bb * 64 + dl) * 4096 + tt * 64 + lane] = tile[lane][dl];
    }
  } else {
    int j = (blockIdx.x - n_trans) * NTH + threadIdx.x;   // 0..4095
    double ang = -(2.0 * 3.14159265358979323846 / 4096.0) * (double)j;
    double s, c;
    sincos(ang, &s, &c);
    Wt[j] = make_float2((float)c, (float)s);
    int jr = (int)(__brev((unsigned)j) >> 20);            // bitrev12
    int jrn = (4096 - jr) & 4095;
#pragma unroll
    for (int k = 0; k < 5; ++k) {
      float m1 = mask_f32(k, jr);
      float m2 = mask_f32(k, jrn);
      Mdr[k * 4096 + j] = (float)(((double)m1 + (double)m2) * (0.5 / 4096.0));
    }
  }
}

// ---------------- FFT building blocks (f32) ----------------
template <int S, bool INV>
__device__ __forceinline__ void fft_stage(float* __restrict__ SRe, float* __restrict__ SIm,
                                          const float2* __restrict__ Wt, int tid) {
  const int LOG = 9 - 3 * S;
  const int sub = 1 << LOG;
#pragma unroll
  for (int gi = 0; gi < 2; ++gi) {
    const int g = tid + 256 * gi;
    const int b_hi = g >> LOG;
    const int b_lo = g & (sub - 1);
    const int base = b_hi * (sub << 3) + b_lo;
    int idx[8];
    float ar[8], ai[8];
#pragma unroll
    for (int q = 0; q < 8; ++q) {
      idx[q] = PHYS(base + q * sub);
      ar[q] = SRe[idx[q]];
      ai[q] = SIm[idx[q]];
    }
    float2 t1[4], t2[2], t3;
#pragma unroll
    for (int q = 0; q < 4; ++q) t1[q] = Wt[(b_lo + q * sub) << (3 * S)];
    t2[0] = Wt[b_lo << (3 * S + 1)];
    t2[1] = Wt[(b_lo + sub) << (3 * S + 1)];
    t3 = Wt[b_lo << (3 * S + 2)];
    if (!INV) {
#pragma unroll
      for (int q = 0; q < 4; ++q) {
        float ur = ar[q] - ar[q + 4], ui = ai[q] - ai[q + 4];
        ar[q] += ar[q + 4]; ai[q] += ai[q + 4];
        ar[q + 4] = ur * t1[q].x - ui * t1[q].y;
        ai[q + 4] = ur * t1[q].y + ui * t1[q].x;
      }
#pragma unroll
      for (int h = 0; h < 8; h += 4)
#pragma unroll
        for (int qq = 0; qq < 2; ++qq) {
          int q = h + qq;
          float ur = ar[q] - ar[q + 2], ui = ai[q] - ai[q + 2];
          ar[q] += ar[q + 2]; ai[q] += ai[q + 2];
          ar[q + 2] = ur * t2[qq].x - ui * t2[qq].y;
          ai[q + 2] = ur * t2[qq].y + ui * t2[qq].x;
        }
#pragma unroll
      for (int q = 0; q < 8; q += 2) {
        float ur = ar[q] - ar[q + 1], ui = ai[q] - ai[q + 1];
        ar[q] += ar[q + 1]; ai[q] += ai[q + 1];
        ar[q + 1] = ur * t3.x - ui * t3.y;
        ai[q + 1] = ur * t3.y + ui * t3.x;
      }
    } else {
#pragma unroll
      for (int q = 0; q < 8; q += 2) {
        float br = ar[q + 1] * t3.x + ai[q + 1] * t3.y;
        float bi = ai[q + 1] * t3.x - ar[q + 1] * t3.y;
        ar[q + 1] = ar[q] - br; ai[q + 1] = ai[q] - bi;
        ar[q] += br; ai[q] += bi;
      }
#pragma unroll
      for (int h = 0; h < 8; h += 4)
#pragma unroll
        for (int qq = 0; qq < 2; ++qq) {
          int q = h + qq;
          float br = ar[q + 2] * t2[qq].x + ai[q + 2] * t2[qq].y;
          float bi = ai[q + 2] * t2[qq].x - ar[q + 2] * t2[qq].y;
          ar[q + 2] = ar[q] - br; ai[q + 2] = ai[q] - bi;
          ar[q] += br; ai[q] += bi;
        }
#pragma unroll
      for (int q = 0; q < 4; ++q) {
        float br = ar[q + 4] * t1[q].x + ai[q + 4] * t1[q].y;
        float bi = ai[q + 4] * t1[q].x - ar[q + 4] * t1[q].y;
        ar[q + 4] = ar[q] - br; ai[q + 4] = ai[q] - bi;
        ar[q] += br; ai[q] += bi;
      }
    }
#pragma unroll
    for (int q = 0; q < 8; ++q) { SRe[idx[q]] = ar[q]; SIm[idx[q]] = ai[q]; }
  }
}

__device__ __forceinline__ void s3_fwd(float* ar, float* ai, const float2* __restrict__ Wt) {
  float2 t1[4];
#pragma unroll
  for (int q = 0; q < 4; ++q) t1[q] = Wt[q << 9];
  float2 t20 = Wt[0], t21 = Wt[1 << 10];
#pragma unroll
  for (int q = 0; q < 4; ++q) {
    float ur = ar[q] - ar[q + 4], ui = ai[q] - ai[q + 4];
    ar[q] += ar[q + 4]; ai[q] += ai[q + 4];
    ar[q + 4] = ur * t1[q].x - ui * t1[q].y;
    ai[q + 4] = ur * t1[q].y + ui * t1[q].x;
  }
#pragma unroll
  for (int h = 0; h < 8; h += 4)
#pragma unroll
    for (int qq = 0; qq < 2; ++qq) {
      int q = h + qq;
      float2 t = qq ? t21 : t20;
      float ur = ar[q] - ar[q + 2], ui = ai[q] - ai[q + 2];
      ar[q] += ar[q + 2]; ai[q] += ai[q + 2];
      ar[q + 2] = ur * t.x - ui * t.y;
      ai[q + 2] = ur * t.y + ui * t.x;
    }
#pragma unroll
  for (int q = 0; q < 8; q += 2) {
    float ur = ar[q] - ar[q + 1], ui = ai[q] - ai[q + 1];
    ar[q] += ar[q + 1]; ai[q] += ai[q + 1];
    ar[q + 1] = ur; ai[q + 1] = ui;
  }
}

__device__ __forceinline__ void s3_inv(float* ar, float* ai, const float2* __restrict__ Wt) {
  float2 t1[4];
#pragma unroll
  for (int q = 0; q < 4; ++q) t1[q] = Wt[q << 9];
  float2 t20 = Wt[0], t21 = Wt[1 << 10];
#pragma unroll
  for (int q = 0; q < 8; q += 2) {
    float br = ar[q + 1], bi = ai[q + 1];
    ar[q + 1] = ar[q] - br; ai[q + 1] = ai[q] - bi;
    ar[q] += br; ai[q] += bi;
  }
#pragma unroll
  for (int h = 0; h < 8; h += 4)
#pragma unroll
    for (int qq = 0; qq < 2; ++qq) {
      int q = h + qq;
      float2 t = qq ? t21 : t20;
      float br = ar[q + 2] * t.x + ai[q + 2] * t.y;
      float bi = ai[q + 2] * t.x - ar[q + 2] * t.y;
      ar[q + 2] = ar[q] - br; ai[q + 2] = ai[q] - bi;
      ar[q] += br; ai[q] += bi;
    }
#pragma unroll
  for (int q = 0; q < 4; ++q) {
    float br = ar[q + 4] * t1[q].x + ai[q + 4] * t1[q].y;
    float bi = ai[q + 4] * t1[q].x - ar[q + 4] * t1[q].y;
    ar[q + 4] = ar[q] - br; ai[q + 4] = ai[q] - bi;
    ar[q] += br; ai[q] += bi;
  }
}

__device__ __forceinline__ void corr_write(float* o, const float* st, int j) {
  const int k = (int)((440700928u >> (3 * j)) & 7u);
  const int l = (int)((611428561u >> (3 * j)) & 7u);
  const float Sk = st[k], Sl = st[l];
  const int offk = (k * (11 - k)) >> 1;
  const int offl = (l * (11 - l)) >> 1;
  const float Skl = st[5 + offk + (l - k)];
  const float Skk = st[5 + offk];
  const float Sll = st[5 + offl];
  const float invT = 1.0f / 4096.0f;
  float cov = Skl - Sk * Sl * invT;
  float vk = Skk - Sk * Sk * invT;
  float vl = Sll - Sl * Sl * invT;
  float dk = sqrtf(fmaxf(vk, 0.f)), dl = sqrtf(fmaxf(vl, 0.f));
  float den = dk * dl;
  float corr = den > 0.f ? cov / den : 0.f;
  o[36 + j] = fminf(1.f, fmaxf(-1.f, corr));
}

// ---------------- main kernel: one block per (b, d-pair) ----------------
// LDS = 17408 + 17408 + 19456 = 54272 B -> 2 blocks/CU (LDS would allow 3,
// but VGPR ~230 -> 2 waves/EU pins us at 2; that's the no-spill optimum).
__global__ void __launch_bounds__(NTH, 1)
tf_main(const float* __restrict__ x,
        const float* __restrict__ xT, int use_xt,
        const float2* __restrict__ Wt,
        const float* __restrict__ Mdr,
        float* __restrict__ out) {
  __shared__ float SRe[4352];
  __shared__ float SIm[4352];
  __shared__ unsigned char hist[NTH * 76];

  const int tid = threadIdx.x;
  const int beta = blockIdx.x;
  const int b = beta >> 5;
  const int dA = (beta & 31) * 2;

  {  // zero own hist slice (76 B, dword-aligned)
    unsigned int* hw = (unsigned int*)(hist + tid * 76);
#pragma unroll
    for (int i = 0; i < 19; ++i) hw[i] = 0u;
  }

  // ---- stage x (two series -> complex) ----
  if (use_xt) {
    const float4* ra = (const float4*)(xT + (size_t)(b * 64 + dA) * 4096);
    const float4* rb = (const float4*)(xT + (size_t)(b * 64 + dA + 1) * 4096);
    for (int t4 = tid; t4 < 1024; t4 += NTH) {
      float4 va = ra[t4], vb = rb[t4];
      int t = t4 * 4;
      SRe[PHYS(t)] = va.x;     SIm[PHYS(t)] = vb.x;
      SRe[PHYS(t + 1)] = va.y; SIm[PHYS(t + 1)] = vb.y;
      SRe[PHYS(t + 2)] = va.z; SIm[PHYS(t + 2)] = vb.z;
      SRe[PHYS(t + 3)] = va.w; SIm[PHYS(t + 3)] = vb.w;
    }
  } else {
    const float2* xp = (const float2*)(x + (size_t)b * 4096 * 64 + dA);
    for (int t = tid; t < 4096; t += NTH) {
      float2 v = xp[(size_t)t * 32];
      SRe[PHYS(t)] = v.x;
      SIm[PHYS(t)] = v.y;
    }
  }
  __syncthreads();

  // ---- forward FFT: stages s=0..2 in LDS, s=3 in regs ----
  fft_stage<0, false>(SRe, SIm, Wt, tid); __syncthreads();
  fft_stage<1, false>(SRe, SIm, Wt, tid); __syncthreads();
  fft_stage<2, false>(SRe, SIm, Wt, tid); __syncthreads();

  float Fr[16], Fi[16];
#pragma unroll
  for (int j = 0; j < 16; ++j) {
    int p = PHYS(tid * 16 + j);
    Fr[j] = SRe[p]; Fi[j] = SIm[p];
  }
  s3_fwd(&Fr[0], &Fi[0], Wt);
  s3_fwd(&Fr[8], &Fi[8], Wt);
  // Fr/Fi hold spectrum at bit-reversed slots [16*tid, 16*tid+16)

  float eA[80], eB[80];   // full f32 energy stash (160 VGPRs) -- no cap, no spill

#pragma unroll
  for (int k = 0; k < 5; ++k) {
    float Zr[16], Zi[16];
#pragma unroll
    for (int j = 0; j < 16; ++j) {
      float m = Mdr[k * 4096 + tid * 16 + j];
      Zr[j] = Fr[j] * m; Zi[j] = Fi[j] * m;
    }
    s3_inv(&Zr[0], &Zi[0], Wt);
    s3_inv(&Zr[8], &Zi[8], Wt);
    __syncthreads();  // previous band's readers done before overwrite
#pragma unroll
    for (int j = 0; j < 16; ++j) {
      int p = PHYS(tid * 16 + j);
      SRe[p] = Zr[j]; SIm[p] = Zi[j];
    }
    __syncthreads();
    fft_stage<2, true>(SRe, SIm, Wt, tid); __syncthreads();
    fft_stage<1, true>(SRe, SIm, Wt, tid); __syncthreads();
    fft_stage<0, true>(SRe, SIm, Wt, tid); __syncthreads();
    // SRe[t] = modes_a[t], SIm[t] = modes_b[t] (natural order)

    // ---- band pass: ordinal patterns + energy stash ----
    {
      const int t0 = tid * 16;
      float a0 = SRe[PHYS(t0)], a1 = SRe[PHYS(t0 + 1)];
      float c0 = SIm[PHYS(t0)], c1 = SIm[PHYS(t0 + 1)];
      eA[k * 16 + 0] = a0 * a0; eA[k * 16 + 1] = a1 * a1;
      eB[k * 16 + 0] = c0 * c0; eB[k * 16 + 1] = c1 * c1;
      int pa = 0, pb = 0;
      unsigned char* myh = hist + tid * 76;
#pragma unroll
      for (int step = 0; step <= 16; ++step) {
        const int w = t0 + step;
        if (w < 4094) {
          float a2 = SRe[PHYS(w + 2)];
          float c2 = SIm[PHYS(w + 2)];
          if (step <= 13) {
            eA[k * 16 + step + 2] = a2 * a2;
            eB[k * 16 + step + 2] = c2 * c2;
          }
          int ia = (int)(a0 <= a1) | ((int)(a0 <= a2) << 1) | ((int)(a1 <= a2) << 2);
          int ca = (int)((537125u >> (3 * ia)) & 7u);
          int ib = (int)(c0 <= c1) | ((int)(c0 <= c2) << 1) | ((int)(c1 <= c2) << 2);
          int cb = (int)((537125u >> (3 * ib)) & 7u);
          if (step >= 1) { myh[pa * 6 + ca] += 1; myh[36 + pb * 6 + cb] += 1; }
          pa = ca; pb = cb;
          a0 = a1; a1 = a2; c0 = c1; c1 = c2;
        }
      }
    }
  }
  __syncthreads();   // all band-pass LDS reads done -> SRe/SIm reusable

  // epilogue scratch overlaid on FFT buffers
  float* red = SIm;                        // [4][40]
  float* stats = SIm + 160;                // 40
  float* rowinv = SIm + 200;               // 12
  unsigned int* histf = (unsigned int*)SRe;  // 72

  // ---- moments ----
  float acc[40];
#pragma unroll
  for (int k = 0; k < 5; ++k) {
    float sA = 0.f, sB = 0.f;
#pragma unroll
    for (int i = 0; i < 16; ++i) { sA += eA[k * 16 + i]; sB += eB[k * 16 + i]; }
    acc[k] = sA; acc[20 + k] = sB;
  }
  {
    int id5 = 5;
#pragma unroll
    for (int k = 0; k < 5; ++k)
#pragma unroll
      for (int l = k; l < 5; ++l) {
        float sA = 0.f, sB = 0.f;
#pragma unroll
        for (int i = 0; i < 16; ++i) {
          sA += eA[k * 16 + i] * eA[l * 16 + i];
          sB += eB[k * 16 + i] * eB[l * 16 + i];
        }
        acc[id5] = sA; acc[20 + id5] = sB; ++id5;
      }
  }
  const int lane = tid & 63, wv = tid >> 6;
#pragma unroll
  for (int j = 0; j < 40; ++j) {
    float v = acc[j];
    v += __shfl_down(v, 32, 64);
    v += __shfl_down(v, 16, 64);
    v += __shfl_down(v, 8, 64);
    v += __shfl_down(v, 4, 64);
    v += __shfl_down(v, 2, 64);
    v += __shfl_down(v, 1, 64);
    if (lane == 0) red[wv * 40 + j] = v;
  }
  __syncthreads();
  if (tid < 40) stats[tid] = red[tid] + red[40 + tid] + red[80 + tid] + red[120 + tid];
  if (tid < 72) {
    unsigned int s = 0;
    for (int i = 0; i < 256; ++i) s += (unsigned int)hist[i * 76 + tid];
    histf[tid] = s;
  }
  __syncthreads();
  if (tid < 12) {
    int base0 = (tid < 6 ? 0 : 36) + (tid % 6) * 6;
    float rs = (float)(histf[base0] + histf[base0 + 1] + histf[base0 + 2] +
                       histf[base0 + 3] + histf[base0 + 4] + histf[base0 + 5]);
    rowinv[tid] = rs > 0.f ? 1.0f / rs : 1.0f;
  }
  __syncthreads();

  float* oA = out + (size_t)(b * 64 + dA) * 46;
  float* oB = oA + 46;
  if (tid < 36) oA[tid] = (float)histf[tid] * rowinv[tid / 6];
  if (tid >= 64 && tid < 100) {
    int j = tid - 64;
    oB[j] = (float)histf[36 + j] * rowinv[6 + j / 6];
  }
  if (tid >= 128 && tid < 138) corr_write(oA, stats, tid - 128);
  if (tid >= 160 && tid < 170) corr_write(oB, stats + 20, tid - 160);
}

// ---------------- launch ----------------
extern "C" void kernel_launch(void* const* d_in, const int* in_sizes, int n_in,
                              void* d_out, int out_size, void* d_ws, size_t ws_size,
                              hipStream_t stream) {
  (void)in_sizes; (void)n_in; (void)out_size;
  const float* x = (const float*)d_in[0];
  float* out = (float*)d_out;
  char* ws = (char*)d_ws;

  float2* Wt = (float2*)ws;                      // 32 KB
  float* Mdr = (float*)(ws + 32768);             // 80 KB
  float* xT = (float*)(ws + 131072);             // 16 MB
  int use_xt = (ws_size >= (size_t)(131072 + 16 * 64 * 4096 * 4)) ? 1 : 0;
  int n_trans = use_xt ? 1024 : 0;

  setup_k<<<n_trans + 16, NTH, 0, stream>>>(x, xT, Wt, Mdr, n_trans);
  tf_main<<<512, NTH, 0, stream>>>(x, xT, use_xt, Wt, Mdr, out);
}

// Round 6
// 226.826 us; speedup vs baseline: 1.1193x; 1.1193x over previous
//
#include <hip/hip_runtime.h>
#include <math.h>

// f32 FFT pipeline. Register-allocator history:
//   r3: launch_bounds(256,2)  -> arch capped 128, 160-f32 stash spilled (68 MB scratch)
//   r4: waves_per_eu(3,8)     -> compiler chose 84 VGPR (open range!), spilled 131 MB
//   r5: launch_bounds(256,1)  -> no spill (VGPR 184 arch) but total unified alloc
//                                >256/wave -> 1 block/CU (Occupancy 11.6%), 207 us
// This round: f16x2 energy stash (numerics proven r4: absmax 3.9e-3, 5x margin)
// cuts true demand to ~160, and waves_per_eu(3,3) -- a CLOSED range -- pins the
// cap at exactly 168 VGPRs: no spill, no sub-cap gambling, 3 waves/EU.
// LDS 54272 B x 3 = 162816 <= 163840 -> 3 blocks/CU target.

#define NTH 256
#define PHYS(i) ((i) + ((i) >> 4))

typedef _Float16 f16x2 __attribute__((ext_vector_type(2)));

__device__ __forceinline__ void seth(f16x2* e, int idx, float v) {
  if (idx & 1) e[idx >> 1].y = (_Float16)v;
  else         e[idx >> 1].x = (_Float16)v;
}
__device__ __forceinline__ float geth(const f16x2* e, int idx) {
  return (idx & 1) ? (float)e[idx >> 1].y : (float)e[idx >> 1].x;
}

// ---------------- fused setup: transpose + tables ----------------
__device__ __forceinline__ float mask_f32(int k, int j) {
  // replicate reference: freqs=fftfreq(4096).astype(f32), centers f32, /0.2f, expf
  float f = (float)((j < 2048) ? j : (j - 4096)) * (1.0f / 4096.0f);
  float c = ((float)k - 2.5f) / 5.0f;
  float df = fabsf(f - c);
  float q = df / 0.2f;
  return expf(-0.5f * (q * q));
}

__global__ void setup_k(const float* __restrict__ x, float* __restrict__ xT,
                        float2* __restrict__ Wt, float* __restrict__ Mdr, int n_trans) {
  __shared__ float tile[64][65];
  if ((int)blockIdx.x < n_trans) {
    int bb = blockIdx.x >> 6;
    int tt = blockIdx.x & 63;
    int lane = threadIdx.x & 63;
    int grp = threadIdx.x >> 6;
#pragma unroll
    for (int r = 0; r < 16; ++r) {
      int tl = grp + 4 * r;
      tile[tl][lane] = x[((size_t)bb * 4096 + tt * 64 + tl) * 64 + lane];
    }
    __syncthreads();
#pragma unroll
    for (int r = 0; r < 16; ++r) {
      int dl = grp + 4 * r;
      xT[((size_t)bb * 64 + dl) * 4096 + tt * 64 + lane] = tile[lane][dl];
    }
  } else {
    int j = (blockIdx.x - n_trans) * NTH + threadIdx.x;   // 0..4095
    double ang = -(2.0 * 3.14159265358979323846 / 4096.0) * (double)j;
    double s, c;
    sincos(ang, &s, &c);
    Wt[j] = make_float2((float)c, (float)s);
    int jr = (int)(__brev((unsigned)j) >> 20);            // bitrev12
    int jrn = (4096 - jr) & 4095;
#pragma unroll
    for (int k = 0; k < 5; ++k) {
      float m1 = mask_f32(k, jr);
      float m2 = mask_f32(k, jrn);
      Mdr[k * 4096 + j] = (float)(((double)m1 + (double)m2) * (0.5 / 4096.0));
    }
  }
}

// ---------------- FFT building blocks (f32) ----------------
template <int S, bool INV>
__device__ __forceinline__ void fft_stage(float* __restrict__ SRe, float* __restrict__ SIm,
                                          const float2* __restrict__ Wt, int tid) {
  const int LOG = 9 - 3 * S;
  const int sub = 1 << LOG;
#pragma unroll
  for (int gi = 0; gi < 2; ++gi) {
    const int g = tid + 256 * gi;
    const int b_hi = g >> LOG;
    const int b_lo = g & (sub - 1);
    const int base = b_hi * (sub << 3) + b_lo;
    int idx[8];
    float ar[8], ai[8];
#pragma unroll
    for (int q = 0; q < 8; ++q) {
      idx[q] = PHYS(base + q * sub);
      ar[q] = SRe[idx[q]];
      ai[q] = SIm[idx[q]];
    }
    float2 t1[4], t2[2], t3;
#pragma unroll
    for (int q = 0; q < 4; ++q) t1[q] = Wt[(b_lo + q * sub) << (3 * S)];
    t2[0] = Wt[b_lo << (3 * S + 1)];
    t2[1] = Wt[(b_lo + sub) << (3 * S + 1)];
    t3 = Wt[b_lo << (3 * S + 2)];
    if (!INV) {
#pragma unroll
      for (int q = 0; q < 4; ++q) {
        float ur = ar[q] - ar[q + 4], ui = ai[q] - ai[q + 4];
        ar[q] += ar[q + 4]; ai[q] += ai[q + 4];
        ar[q + 4] = ur * t1[q].x - ui * t1[q].y;
        ai[q + 4] = ur * t1[q].y + ui * t1[q].x;
      }
#pragma unroll
      for (int h = 0; h < 8; h += 4)
#pragma unroll
        for (int qq = 0; qq < 2; ++qq) {
          int q = h + qq;
          float ur = ar[q] - ar[q + 2], ui = ai[q] - ai[q + 2];
          ar[q] += ar[q + 2]; ai[q] += ai[q + 2];
          ar[q + 2] = ur * t2[qq].x - ui * t2[qq].y;
          ai[q + 2] = ur * t2[qq].y + ui * t2[qq].x;
        }
#pragma unroll
      for (int q = 0; q < 8; q += 2) {
        float ur = ar[q] - ar[q + 1], ui = ai[q] - ai[q + 1];
        ar[q] += ar[q + 1]; ai[q] += ai[q + 1];
        ar[q + 1] = ur * t3.x - ui * t3.y;
        ai[q + 1] = ur * t3.y + ui * t3.x;
      }
    } else {
#pragma unroll
      for (int q = 0; q < 8; q += 2) {
        float br = ar[q + 1] * t3.x + ai[q + 1] * t3.y;
        float bi = ai[q + 1] * t3.x - ar[q + 1] * t3.y;
        ar[q + 1] = ar[q] - br; ai[q + 1] = ai[q] - bi;
        ar[q] += br; ai[q] += bi;
      }
#pragma unroll
      for (int h = 0; h < 8; h += 4)
#pragma unroll
        for (int qq = 0; qq < 2; ++qq) {
          int q = h + qq;
          float br = ar[q + 2] * t2[qq].x + ai[q + 2] * t2[qq].y;
          float bi = ai[q + 2] * t2[qq].x - ar[q + 2] * t2[qq].y;
          ar[q + 2] = ar[q] - br; ai[q + 2] = ai[q] - bi;
          ar[q] += br; ai[q] += bi;
        }
#pragma unroll
      for (int q = 0; q < 4; ++q) {
        float br = ar[q + 4] * t1[q].x + ai[q + 4] * t1[q].y;
        float bi = ai[q + 4] * t1[q].x - ar[q + 4] * t1[q].y;
        ar[q + 4] = ar[q] - br; ai[q + 4] = ai[q] - bi;
        ar[q] += br; ai[q] += bi;
      }
    }
#pragma unroll
    for (int q = 0; q < 8; ++q) { SRe[idx[q]] = ar[q]; SIm[idx[q]] = ai[q]; }
  }
}

__device__ __forceinline__ void s3_fwd(float* ar, float* ai, const float2* __restrict__ Wt) {
  float2 t1[4];
#pragma unroll
  for (int q = 0; q < 4; ++q) t1[q] = Wt[q << 9];
  float2 t20 = Wt[0], t21 = Wt[1 << 10];
#pragma unroll
  for (int q = 0; q < 4; ++q) {
    float ur = ar[q] - ar[q + 4], ui = ai[q] - ai[q + 4];
    ar[q] += ar[q + 4]; ai[q] += ai[q + 4];
    ar[q + 4] = ur * t1[q].x - ui * t1[q].y;
    ai[q + 4] = ur * t1[q].y + ui * t1[q].x;
  }
#pragma unroll
  for (int h = 0; h < 8; h += 4)
#pragma unroll
    for (int qq = 0; qq < 2; ++qq) {
      int q = h + qq;
      float2 t = qq ? t21 : t20;
      float ur = ar[q] - ar[q + 2], ui = ai[q] - ai[q + 2];
      ar[q] += ar[q + 2]; ai[q] += ai[q + 2];
      ar[q + 2] = ur * t.x - ui * t.y;
      ai[q + 2] = ur * t.y + ui * t.x;
    }
#pragma unroll
  for (int q = 0; q < 8; q += 2) {
    float ur = ar[q] - ar[q + 1], ui = ai[q] - ai[q + 1];
    ar[q] += ar[q + 1]; ai[q] += ai[q + 1];
    ar[q + 1] = ur; ai[q + 1] = ui;
  }
}

__device__ __forceinline__ void s3_inv(float* ar, float* ai, const float2* __restrict__ Wt) {
  float2 t1[4];
#pragma unroll
  for (int q = 0; q < 4; ++q) t1[q] = Wt[q << 9];
  float2 t20 = Wt[0], t21 = Wt[1 << 10];
#pragma unroll
  for (int q = 0; q < 8; q += 2) {
    float br = ar[q + 1], bi = ai[q + 1];
    ar[q + 1] = ar[q] - br; ai[q + 1] = ai[q] - bi;
    ar[q] += br; ai[q] += bi;
  }
#pragma unroll
  for (int h = 0; h < 8; h += 4)
#pragma unroll
    for (int qq = 0; qq < 2; ++qq) {
      int q = h + qq;
      float2 t = qq ? t21 : t20;
      float br = ar[q + 2] * t.x + ai[q + 2] * t.y;
      float bi = ai[q + 2] * t.x - ar[q + 2] * t.y;
      ar[q + 2] = ar[q] - br; ai[q + 2] = ai[q] - bi;
      ar[q] += br; ai[q] += bi;
    }
#pragma unroll
  for (int q = 0; q < 4; ++q) {
    float br = ar[q + 4] * t1[q].x + ai[q + 4] * t1[q].y;
    float bi = ai[q + 4] * t1[q].x - ar[q + 4] * t1[q].y;
    ar[q + 4] = ar[q] - br; ai[q + 4] = ai[q] - bi;
    ar[q] += br; ai[q] += bi;
  }
}

__device__ __forceinline__ void corr_write(float* o, const float* st, int j) {
  const int k = (int)((440700928u >> (3 * j)) & 7u);
  const int l = (int)((611428561u >> (3 * j)) & 7u);
  const float Sk = st[k], Sl = st[l];
  const int offk = (k * (11 - k)) >> 1;
  const int offl = (l * (11 - l)) >> 1;
  const float Skl = st[5 + offk + (l - k)];
  const float Skk = st[5 + offk];
  const float Sll = st[5 + offl];
  const float invT = 1.0f / 4096.0f;
  float cov = Skl - Sk * Sl * invT;
  float vk = Skk - Sk * Sk * invT;
  float vl = Sll - Sl * Sl * invT;
  float dk = sqrtf(fmaxf(vk, 0.f)), dl = sqrtf(fmaxf(vl, 0.f));
  float den = dk * dl;
  float corr = den > 0.f ? cov / den : 0.f;
  o[36 + j] = fminf(1.f, fmaxf(-1.f, corr));
}

// ---------------- main kernel: one block per (b, d-pair) ----------------
// LDS = 17408 + 17408 + 19456 = 54272 B; x3 = 162816 <= 163840 -> 3 blocks/CU.
// waves_per_eu(3,3): closed range -> VGPR cap exactly 168, fits f16-stash demand.
__attribute__((amdgpu_waves_per_eu(3, 3)))
__global__ void __launch_bounds__(NTH)
tf_main(const float* __restrict__ x,
        const float* __restrict__ xT, int use_xt,
        const float2* __restrict__ Wt,
        const float* __restrict__ Mdr,
        float* __restrict__ out) {
  __shared__ float SRe[4352];
  __shared__ float SIm[4352];
  __shared__ unsigned char hist[NTH * 76];

  const int tid = threadIdx.x;
  const int beta = blockIdx.x;
  const int b = beta >> 5;
  const int dA = (beta & 31) * 2;

  {  // zero own hist slice (76 B, dword-aligned)
    unsigned int* hw = (unsigned int*)(hist + tid * 76);
#pragma unroll
    for (int i = 0; i < 19; ++i) hw[i] = 0u;
  }

  // ---- stage x (two series -> complex) ----
  if (use_xt) {
    const float4* ra = (const float4*)(xT + (size_t)(b * 64 + dA) * 4096);
    const float4* rb = (const float4*)(xT + (size_t)(b * 64 + dA + 1) * 4096);
    for (int t4 = tid; t4 < 1024; t4 += NTH) {
      float4 va = ra[t4], vb = rb[t4];
      int t = t4 * 4;
      SRe[PHYS(t)] = va.x;     SIm[PHYS(t)] = vb.x;
      SRe[PHYS(t + 1)] = va.y; SIm[PHYS(t + 1)] = vb.y;
      SRe[PHYS(t + 2)] = va.z; SIm[PHYS(t + 2)] = vb.z;
      SRe[PHYS(t + 3)] = va.w; SIm[PHYS(t + 3)] = vb.w;
    }
  } else {
    const float2* xp = (const float2*)(x + (size_t)b * 4096 * 64 + dA);
    for (int t = tid; t < 4096; t += NTH) {
      float2 v = xp[(size_t)t * 32];
      SRe[PHYS(t)] = v.x;
      SIm[PHYS(t)] = v.y;
    }
  }
  __syncthreads();

  // ---- forward FFT: stages s=0..2 in LDS, s=3 in regs ----
  fft_stage<0, false>(SRe, SIm, Wt, tid); __syncthreads();
  fft_stage<1, false>(SRe, SIm, Wt, tid); __syncthreads();
  fft_stage<2, false>(SRe, SIm, Wt, tid); __syncthreads();

  float Fr[16], Fi[16];
#pragma unroll
  for (int j = 0; j < 16; ++j) {
    int p = PHYS(tid * 16 + j);
    Fr[j] = SRe[p]; Fi[j] = SIm[p];
  }
  s3_fwd(&Fr[0], &Fi[0], Wt);
  s3_fwd(&Fr[8], &Fi[8], Wt);
  // Fr/Fi hold spectrum at bit-reversed slots [16*tid, 16*tid+16)

  f16x2 eA2[40], eB2[40];   // packed energy stash: 80 VGPRs total

#pragma unroll
  for (int k = 0; k < 5; ++k) {
    float Zr[16], Zi[16];
#pragma unroll
    for (int j = 0; j < 16; ++j) {
      float m = Mdr[k * 4096 + tid * 16 + j];
      Zr[j] = Fr[j] * m; Zi[j] = Fi[j] * m;
    }
    s3_inv(&Zr[0], &Zi[0], Wt);
    s3_inv(&Zr[8], &Zi[8], Wt);
    __syncthreads();  // previous band's readers done before overwrite
#pragma unroll
    for (int j = 0; j < 16; ++j) {
      int p = PHYS(tid * 16 + j);
      SRe[p] = Zr[j]; SIm[p] = Zi[j];
    }
    __syncthreads();
    fft_stage<2, true>(SRe, SIm, Wt, tid); __syncthreads();
    fft_stage<1, true>(SRe, SIm, Wt, tid); __syncthreads();
    fft_stage<0, true>(SRe, SIm, Wt, tid); __syncthreads();
    // SRe[t] = modes_a[t], SIm[t] = modes_b[t] (natural order)

    // ---- band pass: ordinal patterns + energy stash ----
    {
      const int t0 = tid * 16;
      float a0 = SRe[PHYS(t0)], a1 = SRe[PHYS(t0 + 1)];
      float c0 = SIm[PHYS(t0)], c1 = SIm[PHYS(t0 + 1)];
      seth(eA2, k * 16 + 0, a0 * a0); seth(eA2, k * 16 + 1, a1 * a1);
      seth(eB2, k * 16 + 0, c0 * c0); seth(eB2, k * 16 + 1, c1 * c1);
      int pa = 0, pb = 0;
      unsigned char* myh = hist + tid * 76;
#pragma unroll
      for (int step = 0; step <= 16; ++step) {
        const int w = t0 + step;
        if (w < 4094) {
          float a2 = SRe[PHYS(w + 2)];
          float c2 = SIm[PHYS(w + 2)];
          if (step <= 13) {
            seth(eA2, k * 16 + step + 2, a2 * a2);
            seth(eB2, k * 16 + step + 2, c2 * c2);
          }
          int ia = (int)(a0 <= a1) | ((int)(a0 <= a2) << 1) | ((int)(a1 <= a2) << 2);
          int ca = (int)((537125u >> (3 * ia)) & 7u);
          int ib = (int)(c0 <= c1) | ((int)(c0 <= c2) << 1) | ((int)(c1 <= c2) << 2);
          int cb = (int)((537125u >> (3 * ib)) & 7u);
          if (step >= 1) { myh[pa * 6 + ca] += 1; myh[36 + pb * 6 + cb] += 1; }
          pa = ca; pb = cb;
          a0 = a1; a1 = a2; c0 = c1; c1 = c2;
        }
      }
    }
  }
  __syncthreads();   // all band-pass LDS reads done -> SRe/SIm reusable

  // epilogue scratch overlaid on FFT buffers
  float* red = SIm;                        // [4][40]
  float* stats = SIm + 160;                // 40
  float* rowinv = SIm + 200;               // 12
  unsigned int* histf = (unsigned int*)SRe;  // 72

  // ---- moments (i-outer: unpack 10 f16 at a time) ----
  float acc[40];
#pragma unroll
  for (int j = 0; j < 40; ++j) acc[j] = 0.f;
#pragma unroll
  for (int i = 0; i < 16; ++i) {
    float ea[5], eb[5];
#pragma unroll
    for (int k = 0; k < 5; ++k) {
      ea[k] = geth(eA2, k * 16 + i);
      eb[k] = geth(eB2, k * 16 + i);
    }
    int id5 = 5;
#pragma unroll
    for (int k = 0; k < 5; ++k) {
      acc[k] += ea[k]; acc[20 + k] += eb[k];
#pragma unroll
      for (int l = k; l < 5; ++l) {
        acc[id5] += ea[k] * ea[l];
        acc[20 + id5] += eb[k] * eb[l];
        ++id5;
      }
    }
  }
  const int lane = tid & 63, wv = tid >> 6;
#pragma unroll
  for (int j = 0; j < 40; ++j) {
    float v = acc[j];
    v += __shfl_down(v, 32, 64);
    v += __shfl_down(v, 16, 64);
    v += __shfl_down(v, 8, 64);
    v += __shfl_down(v, 4, 64);
    v += __shfl_down(v, 2, 64);
    v += __shfl_down(v, 1, 64);
    if (lane == 0) red[wv * 40 + j] = v;
  }
  __syncthreads();
  if (tid < 40) stats[tid] = red[tid] + red[40 + tid] + red[80 + tid] + red[120 + tid];
  if (tid < 72) {
    unsigned int s = 0;
    for (int i = 0; i < 256; ++i) s += (unsigned int)hist[i * 76 + tid];
    histf[tid] = s;
  }
  __syncthreads();
  if (tid < 12) {
    int base0 = (tid < 6 ? 0 : 36) + (tid % 6) * 6;
    float rs = (float)(histf[base0] + histf[base0 + 1] + histf[base0 + 2] +
                       histf[base0 + 3] + histf[base0 + 4] + histf[base0 + 5]);
    rowinv[tid] = rs > 0.f ? 1.0f / rs : 1.0f;
  }
  __syncthreads();

  float* oA = out + (size_t)(b * 64 + dA) * 46;
  float* oB = oA + 46;
  if (tid < 36) oA[tid] = (float)histf[tid] * rowinv[tid / 6];
  if (tid >= 64 && tid < 100) {
    int j = tid - 64;
    oB[j] = (float)histf[36 + j] * rowinv[6 + j / 6];
  }
  if (tid >= 128 && tid < 138) corr_write(oA, stats, tid - 128);
  if (tid >= 160 && tid < 170) corr_write(oB, stats + 20, tid - 160);
}

// ---------------- launch ----------------
extern "C" void kernel_launch(void* const* d_in, const int* in_sizes, int n_in,
                              void* d_out, int out_size, void* d_ws, size_t ws_size,
                              hipStream_t stream) {
  (void)in_sizes; (void)n_in; (void)out_size;
  const float* x = (const float*)d_in[0];
  float* out = (float*)d_out;
  char* ws = (char*)d_ws;

  float2* Wt = (float2*)ws;                      // 32 KB
  float* Mdr = (float*)(ws + 32768);             // 80 KB
  float* xT = (float*)(ws + 131072);             // 16 MB
  int use_xt = (ws_size >= (size_t)(131072 + 16 * 64 * 4096 * 4)) ? 1 : 0;
  int n_trans = use_xt ? 1024 : 0;

  setup_k<<<n_trans + 16, NTH, 0, stream>>>(x, xT, Wt, Mdr, n_trans);
  tf_main<<<512, NTH, 0, stream>>>(x, xT, use_xt, Wt, Mdr, out);
}

// Round 7
// 173.369 us; speedup vs baseline: 1.4644x; 1.3083x over previous
//
#include <hip/hip_runtime.h>
#include <math.h>

// Two-kernel split. Rounds 2-6 proved the per-thread 160-element energy stash
// is unallocatable: every occupancy target >1 wave/EU makes the scheduler
// spill it (r3: 68 MB, r4/r6: 131 MB scratch), and uncapped builds blow the
// 256-total/wave cliff to 1 block/CU (r2/r5). Fix: delete the stash.
//   tf_main   : FFT + mask + IFFT + ordinal histogram; streams band energies
//               to workspace E[bd][k][t] as f16 (42 MB, coalesced).
//   moments_k : streams E back (L2/L3-warm), accumulates 20 moments, writes corr.

#define NTH 256
#define PHYS(i) ((i) + ((i) >> 4))

typedef _Float16 f16x8 __attribute__((ext_vector_type(8)));
typedef _Float16 f16x2 __attribute__((ext_vector_type(2)));

// ---------------- fused setup: transpose + tables ----------------
__device__ __forceinline__ float mask_f32(int k, int j) {
  // replicate reference: freqs=fftfreq(4096).astype(f32), centers f32, /0.2f, expf
  float f = (float)((j < 2048) ? j : (j - 4096)) * (1.0f / 4096.0f);
  float c = ((float)k - 2.5f) / 5.0f;
  float df = fabsf(f - c);
  float q = df / 0.2f;
  return expf(-0.5f * (q * q));
}

__global__ void setup_k(const float* __restrict__ x, float* __restrict__ xT,
                        float2* __restrict__ Wt, float* __restrict__ Mdr, int n_trans) {
  __shared__ float tile[64][65];
  if ((int)blockIdx.x < n_trans) {
    int bb = blockIdx.x >> 6;
    int tt = blockIdx.x & 63;
    int lane = threadIdx.x & 63;
    int grp = threadIdx.x >> 6;
#pragma unroll
    for (int r = 0; r < 16; ++r) {
      int tl = grp + 4 * r;
      tile[tl][lane] = x[((size_t)bb * 4096 + tt * 64 + tl) * 64 + lane];
    }
    __syncthreads();
#pragma unroll
    for (int r = 0; r < 16; ++r) {
      int dl = grp + 4 * r;
      xT[((size_t)bb * 64 + dl) * 4096 + tt * 64 + lane] = tile[lane][dl];
    }
  } else {
    int j = (blockIdx.x - n_trans) * NTH + threadIdx.x;   // 0..4095
    double ang = -(2.0 * 3.14159265358979323846 / 4096.0) * (double)j;
    double s, c;
    sincos(ang, &s, &c);
    Wt[j] = make_float2((float)c, (float)s);
    int jr = (int)(__brev((unsigned)j) >> 20);            // bitrev12
    int jrn = (4096 - jr) & 4095;
#pragma unroll
    for (int k = 0; k < 5; ++k) {
      float m1 = mask_f32(k, jr);
      float m2 = mask_f32(k, jrn);
      Mdr[k * 4096 + j] = (float)(((double)m1 + (double)m2) * (0.5 / 4096.0));
    }
  }
}

// ---------------- FFT building blocks (f32) ----------------
template <int S, bool INV>
__device__ __forceinline__ void fft_stage(float* __restrict__ SRe, float* __restrict__ SIm,
                                          const float2* __restrict__ Wt, int tid) {
  const int LOG = 9 - 3 * S;
  const int sub = 1 << LOG;
#pragma unroll
  for (int gi = 0; gi < 2; ++gi) {
    const int g = tid + 256 * gi;
    const int b_hi = g >> LOG;
    const int b_lo = g & (sub - 1);
    const int base = b_hi * (sub << 3) + b_lo;
    int idx[8];
    float ar[8], ai[8];
#pragma unroll
    for (int q = 0; q < 8; ++q) {
      idx[q] = PHYS(base + q * sub);
      ar[q] = SRe[idx[q]];
      ai[q] = SIm[idx[q]];
    }
    float2 t1[4], t2[2], t3;
#pragma unroll
    for (int q = 0; q < 4; ++q) t1[q] = Wt[(b_lo + q * sub) << (3 * S)];
    t2[0] = Wt[b_lo << (3 * S + 1)];
    t2[1] = Wt[(b_lo + sub) << (3 * S + 1)];
    t3 = Wt[b_lo << (3 * S + 2)];
    if (!INV) {
#pragma unroll
      for (int q = 0; q < 4; ++q) {
        float ur = ar[q] - ar[q + 4], ui = ai[q] - ai[q + 4];
        ar[q] += ar[q + 4]; ai[q] += ai[q + 4];
        ar[q + 4] = ur * t1[q].x - ui * t1[q].y;
        ai[q + 4] = ur * t1[q].y + ui * t1[q].x;
      }
#pragma unroll
      for (int h = 0; h < 8; h += 4)
#pragma unroll
        for (int qq = 0; qq < 2; ++qq) {
          int q = h + qq;
          float ur = ar[q] - ar[q + 2], ui = ai[q] - ai[q + 2];
          ar[q] += ar[q + 2]; ai[q] += ai[q + 2];
          ar[q + 2] = ur * t2[qq].x - ui * t2[qq].y;
          ai[q + 2] = ur * t2[qq].y + ui * t2[qq].x;
        }
#pragma unroll
      for (int q = 0; q < 8; q += 2) {
        float ur = ar[q] - ar[q + 1], ui = ai[q] - ai[q + 1];
        ar[q] += ar[q + 1]; ai[q] += ai[q + 1];
        ar[q + 1] = ur * t3.x - ui * t3.y;
        ai[q + 1] = ur * t3.y + ui * t3.x;
      }
    } else {
#pragma unroll
      for (int q = 0; q < 8; q += 2) {
        float br = ar[q + 1] * t3.x + ai[q + 1] * t3.y;
        float bi = ai[q + 1] * t3.x - ar[q + 1] * t3.y;
        ar[q + 1] = ar[q] - br; ai[q + 1] = ai[q] - bi;
        ar[q] += br; ai[q] += bi;
      }
#pragma unroll
      for (int h = 0; h < 8; h += 4)
#pragma unroll
        for (int qq = 0; qq < 2; ++qq) {
          int q = h + qq;
          float br = ar[q + 2] * t2[qq].x + ai[q + 2] * t2[qq].y;
          float bi = ai[q + 2] * t2[qq].x - ar[q + 2] * t2[qq].y;
          ar[q + 2] = ar[q] - br; ai[q + 2] = ai[q] - bi;
          ar[q] += br; ai[q] += bi;
        }
#pragma unroll
      for (int q = 0; q < 4; ++q) {
        float br = ar[q + 4] * t1[q].x + ai[q + 4] * t1[q].y;
        float bi = ai[q + 4] * t1[q].x - ar[q + 4] * t1[q].y;
        ar[q + 4] = ar[q] - br; ai[q + 4] = ai[q] - bi;
        ar[q] += br; ai[q] += bi;
      }
    }
#pragma unroll
    for (int q = 0; q < 8; ++q) { SRe[idx[q]] = ar[q]; SIm[idx[q]] = ai[q]; }
  }
}

__device__ __forceinline__ void s3_fwd(float* ar, float* ai, const float2* __restrict__ Wt) {
  float2 t1[4];
#pragma unroll
  for (int q = 0; q < 4; ++q) t1[q] = Wt[q << 9];
  float2 t20 = Wt[0], t21 = Wt[1 << 10];
#pragma unroll
  for (int q = 0; q < 4; ++q) {
    float ur = ar[q] - ar[q + 4], ui = ai[q] - ai[q + 4];
    ar[q] += ar[q + 4]; ai[q] += ai[q + 4];
    ar[q + 4] = ur * t1[q].x - ui * t1[q].y;
    ai[q + 4] = ur * t1[q].y + ui * t1[q].x;
  }
#pragma unroll
  for (int h = 0; h < 8; h += 4)
#pragma unroll
    for (int qq = 0; qq < 2; ++qq) {
      int q = h + qq;
      float2 t = qq ? t21 : t20;
      float ur = ar[q] - ar[q + 2], ui = ai[q] - ai[q + 2];
      ar[q] += ar[q + 2]; ai[q] += ai[q + 2];
      ar[q + 2] = ur * t.x - ui * t.y;
      ai[q + 2] = ur * t.y + ui * t.x;
    }
#pragma unroll
  for (int q = 0; q < 8; q += 2) {
    float ur = ar[q] - ar[q + 1], ui = ai[q] - ai[q + 1];
    ar[q] += ar[q + 1]; ai[q] += ai[q + 1];
    ar[q + 1] = ur; ai[q + 1] = ui;
  }
}

__device__ __forceinline__ void s3_inv(float* ar, float* ai, const float2* __restrict__ Wt) {
  float2 t1[4];
#pragma unroll
  for (int q = 0; q < 4; ++q) t1[q] = Wt[q << 9];
  float2 t20 = Wt[0], t21 = Wt[1 << 10];
#pragma unroll
  for (int q = 0; q < 8; q += 2) {
    float br = ar[q + 1], bi = ai[q + 1];
    ar[q + 1] = ar[q] - br; ai[q + 1] = ai[q] - bi;
    ar[q] += br; ai[q] += bi;
  }
#pragma unroll
  for (int h = 0; h < 8; h += 4)
#pragma unroll
    for (int qq = 0; qq < 2; ++qq) {
      int q = h + qq;
      float2 t = qq ? t21 : t20;
      float br = ar[q + 2] * t.x + ai[q + 2] * t.y;
      float bi = ai[q + 2] * t.x - ar[q + 2] * t.y;
      ar[q + 2] = ar[q] - br; ai[q + 2] = ai[q] - bi;
      ar[q] += br; ai[q] += bi;
    }
#pragma unroll
  for (int q = 0; q < 4; ++q) {
    float br = ar[q + 4] * t1[q].x + ai[q + 4] * t1[q].y;
    float bi = ai[q + 4] * t1[q].x - ar[q + 4] * t1[q].y;
    ar[q + 4] = ar[q] - br; ai[q + 4] = ai[q] - bi;
    ar[q] += br; ai[q] += bi;
  }
}

__device__ __forceinline__ void corr_write(float* o, const float* st, int j) {
  const int k = (int)((440700928u >> (3 * j)) & 7u);
  const int l = (int)((611428561u >> (3 * j)) & 7u);
  const float Sk = st[k], Sl = st[l];
  const int offk = (k * (11 - k)) >> 1;
  const int offl = (l * (11 - l)) >> 1;
  const float Skl = st[5 + offk + (l - k)];
  const float Skk = st[5 + offk];
  const float Sll = st[5 + offl];
  const float invT = 1.0f / 4096.0f;
  float cov = Skl - Sk * Sl * invT;
  float vk = Skk - Sk * Sk * invT;
  float vl = Sll - Sl * Sl * invT;
  float dk = sqrtf(fmaxf(vk, 0.f)), dl = sqrtf(fmaxf(vl, 0.f));
  float den = dk * dl;
  float corr = den > 0.f ? cov / den : 0.f;
  o[36 + j] = fminf(1.f, fmaxf(-1.f, corr));
}

// ---------------- kernel 1: FFT + ordinal hist + energy stream ----------------
// LDS 54272 B (x3 = 162816 <= 163840 -> 3 blocks/CU); no long-lived register
// arrays -> expected VGPR ~120, no spill, no launch-bounds games.
__global__ void __launch_bounds__(NTH)
tf_main(const float* __restrict__ x,
        const float* __restrict__ xT, int use_xt,
        const float2* __restrict__ Wt,
        const float* __restrict__ Mdr,
        _Float16* __restrict__ E,
        float* __restrict__ out) {
  __shared__ float SRe[4352];
  __shared__ float SIm[4352];
  __shared__ unsigned char hist[NTH * 76];

  const int tid = threadIdx.x;
  const int beta = blockIdx.x;
  const int b = beta >> 5;
  const int dA = (beta & 31) * 2;

  {  // zero own hist slice (76 B, dword-aligned)
    unsigned int* hw = (unsigned int*)(hist + tid * 76);
#pragma unroll
    for (int i = 0; i < 19; ++i) hw[i] = 0u;
  }

  // ---- stage x (two series -> complex) ----
  if (use_xt) {
    const float4* ra = (const float4*)(xT + (size_t)(b * 64 + dA) * 4096);
    const float4* rb = (const float4*)(xT + (size_t)(b * 64 + dA + 1) * 4096);
    for (int t4 = tid; t4 < 1024; t4 += NTH) {
      float4 va = ra[t4], vb = rb[t4];
      int t = t4 * 4;
      SRe[PHYS(t)] = va.x;     SIm[PHYS(t)] = vb.x;
      SRe[PHYS(t + 1)] = va.y; SIm[PHYS(t + 1)] = vb.y;
      SRe[PHYS(t + 2)] = va.z; SIm[PHYS(t + 2)] = vb.z;
      SRe[PHYS(t + 3)] = va.w; SIm[PHYS(t + 3)] = vb.w;
    }
  } else {
    const float2* xp = (const float2*)(x + (size_t)b * 4096 * 64 + dA);
    for (int t = tid; t < 4096; t += NTH) {
      float2 v = xp[(size_t)t * 32];
      SRe[PHYS(t)] = v.x;
      SIm[PHYS(t)] = v.y;
    }
  }
  __syncthreads();

  // ---- forward FFT: stages s=0..2 in LDS, s=3 in regs ----
  fft_stage<0, false>(SRe, SIm, Wt, tid); __syncthreads();
  fft_stage<1, false>(SRe, SIm, Wt, tid); __syncthreads();
  fft_stage<2, false>(SRe, SIm, Wt, tid); __syncthreads();

  float Fr[16], Fi[16];
#pragma unroll
  for (int j = 0; j < 16; ++j) {
    int p = PHYS(tid * 16 + j);
    Fr[j] = SRe[p]; Fi[j] = SIm[p];
  }
  s3_fwd(&Fr[0], &Fi[0], Wt);
  s3_fwd(&Fr[8], &Fi[8], Wt);
  // Fr/Fi hold spectrum at bit-reversed slots [16*tid, 16*tid+16)

#pragma unroll
  for (int k = 0; k < 5; ++k) {
    float Zr[16], Zi[16];
#pragma unroll
    for (int j = 0; j < 16; ++j) {
      float m = Mdr[k * 4096 + tid * 16 + j];
      Zr[j] = Fr[j] * m; Zi[j] = Fi[j] * m;
    }
    s3_inv(&Zr[0], &Zi[0], Wt);
    s3_inv(&Zr[8], &Zi[8], Wt);
    __syncthreads();  // previous band's readers done before overwrite
#pragma unroll
    for (int j = 0; j < 16; ++j) {
      int p = PHYS(tid * 16 + j);
      SRe[p] = Zr[j]; SIm[p] = Zi[j];
    }
    __syncthreads();
    fft_stage<2, true>(SRe, SIm, Wt, tid); __syncthreads();
    fft_stage<1, true>(SRe, SIm, Wt, tid); __syncthreads();
    fft_stage<0, true>(SRe, SIm, Wt, tid); __syncthreads();
    // SRe[t] = modes_a[t], SIm[t] = modes_b[t] (natural order)

    // ---- band pass: ordinal patterns + stream energies to global ----
    {
      const int t0 = tid * 16;
      float a0 = SRe[PHYS(t0)], a1 = SRe[PHYS(t0 + 1)];
      float c0 = SIm[PHYS(t0)], c1 = SIm[PHYS(t0 + 1)];
      _Float16 ehA[16], ehB[16];
      ehA[0] = (_Float16)(a0 * a0); ehA[1] = (_Float16)(a1 * a1);
      ehB[0] = (_Float16)(c0 * c0); ehB[1] = (_Float16)(c1 * c1);
      int pa = 0, pb = 0;
      unsigned char* myh = hist + tid * 76;
#pragma unroll
      for (int step = 0; step <= 16; ++step) {
        const int w = t0 + step;
        if (w < 4094) {
          float a2 = SRe[PHYS(w + 2)];
          float c2 = SIm[PHYS(w + 2)];
          if (step <= 13) {
            ehA[step + 2] = (_Float16)(a2 * a2);
            ehB[step + 2] = (_Float16)(c2 * c2);
          }
          int ia = (int)(a0 <= a1) | ((int)(a0 <= a2) << 1) | ((int)(a1 <= a2) << 2);
          int ca = (int)((537125u >> (3 * ia)) & 7u);
          int ib = (int)(c0 <= c1) | ((int)(c0 <= c2) << 1) | ((int)(c1 <= c2) << 2);
          int cb = (int)((537125u >> (3 * ib)) & 7u);
          if (step >= 1) { myh[pa * 6 + ca] += 1; myh[36 + pb * 6 + cb] += 1; }
          pa = ca; pb = cb;
          a0 = a1; a1 = a2; c0 = c1; c1 = c2;
        }
      }
      // coalesced f16 store: 2x16B per series (row is 4096 halves = 8 KB)
      f16x8* EA = (f16x8*)(E + ((size_t)(b * 64 + dA) * 5 + k) * 4096 + t0);
      f16x8* EB = (f16x8*)(E + ((size_t)(b * 64 + dA + 1) * 5 + k) * 4096 + t0);
      EA[0] = *(f16x8*)&ehA[0]; EA[1] = *(f16x8*)&ehA[8];
      EB[0] = *(f16x8*)&ehB[0]; EB[1] = *(f16x8*)&ehB[8];
    }
  }
  __syncthreads();   // all band-pass LDS reads done -> SRe reusable

  // ---- histogram reduce + tmptm outputs ----
  unsigned int* histf = (unsigned int*)SRe;  // 72
  float* rowinv = SIm;                       // 12
  if (tid < 72) {
    unsigned int s = 0;
    for (int i = 0; i < 256; ++i) s += (unsigned int)hist[i * 76 + tid];
    histf[tid] = s;
  }
  __syncthreads();
  if (tid < 12) {
    int base0 = (tid < 6 ? 0 : 36) + (tid % 6) * 6;
    float rs = (float)(histf[base0] + histf[base0 + 1] + histf[base0 + 2] +
                       histf[base0 + 3] + histf[base0 + 4] + histf[base0 + 5]);
    rowinv[tid] = rs > 0.f ? 1.0f / rs : 1.0f;
  }
  __syncthreads();

  float* oA = out + (size_t)(b * 64 + dA) * 46;
  float* oB = oA + 46;
  if (tid < 36) oA[tid] = (float)histf[tid] * rowinv[tid / 6];
  if (tid >= 64 && tid < 100) {
    int j = tid - 64;
    oB[j] = (float)histf[36 + j] * rowinv[6 + j / 6];
  }
}

// ---------------- kernel 2: stream energies -> moments -> corr ----------------
__global__ void __launch_bounds__(NTH)
moments_k(const _Float16* __restrict__ E, float* __restrict__ out) {
  __shared__ float red[4][20];
  __shared__ float stats[20];
  const int bd = blockIdx.x;
  const int tid = threadIdx.x;
  const f16x2* Eb = (const f16x2*)(E + (size_t)bd * 5 * 4096);

  float acc[20];
#pragma unroll
  for (int j = 0; j < 20; ++j) acc[j] = 0.f;
  for (int i = 0; i < 8; ++i) {
    int t2 = tid + 256 * i;              // half2 index, 0..2047 (coalesced)
    float ex[5], ey[5];
#pragma unroll
    for (int k = 0; k < 5; ++k) {
      f16x2 v = Eb[k * 2048 + t2];
      ex[k] = (float)v.x; ey[k] = (float)v.y;
    }
    int id5 = 5;
#pragma unroll
    for (int k = 0; k < 5; ++k) {
      acc[k] += ex[k] + ey[k];
#pragma unroll
      for (int l = k; l < 5; ++l) {
        acc[id5] += ex[k] * ex[l] + ey[k] * ey[l];
        ++id5;
      }
    }
  }
  const int lane = tid & 63, wv = tid >> 6;
#pragma unroll
  for (int j = 0; j < 20; ++j) {
    float v = acc[j];
    v += __shfl_down(v, 32, 64);
    v += __shfl_down(v, 16, 64);
    v += __shfl_down(v, 8, 64);
    v += __shfl_down(v, 4, 64);
    v += __shfl_down(v, 2, 64);
    v += __shfl_down(v, 1, 64);
    if (lane == 0) red[wv][j] = v;
  }
  __syncthreads();
  if (tid < 20) stats[tid] = red[0][tid] + red[1][tid] + red[2][tid] + red[3][tid];
  __syncthreads();
  if (tid < 10) corr_write(out + (size_t)bd * 46, stats, tid);
}

// ---------------- launch ----------------
extern "C" void kernel_launch(void* const* d_in, const int* in_sizes, int n_in,
                              void* d_out, int out_size, void* d_ws, size_t ws_size,
                              hipStream_t stream) {
  (void)in_sizes; (void)n_in; (void)out_size;
  const float* x = (const float*)d_in[0];
  float* out = (float*)d_out;
  char* ws = (char*)d_ws;

  float2* Wt = (float2*)ws;                      // 32 KB
  float* Mdr = (float*)(ws + 32768);             // 80 KB
  _Float16* E = (_Float16*)(ws + 131072);        // 1024*5*4096*2 = 41.94 MB
  const size_t E_end = 131072 + (size_t)1024 * 5 * 4096 * 2;
  float* xT = (float*)(ws + E_end);              // 16.78 MB (optional)
  int use_xt = (ws_size >= E_end + (size_t)16 * 64 * 4096 * 4) ? 1 : 0;
  int n_trans = use_xt ? 1024 : 0;

  setup_k<<<n_trans + 16, NTH, 0, stream>>>(x, xT, Wt, Mdr, n_trans);
  tf_main<<<512, NTH, 0, stream>>>(x, xT, use_xt, Wt, Mdr, E, out);
  moments_k<<<1024, NTH, 0, stream>>>(E, out);
}

// Round 10
// 121.545 us; speedup vs baseline: 2.0888x; 1.4264x over previous
//
#include <hip/hip_runtime.h>
#include <math.h>

// Three-FFT pipeline with exact Nyquist correction.
// r8/r9 post-mortem: identical deterministic absmax (0.0234375) => arithmetic
// bug, not spill/alignment. The even-symmetrized masks for centers +-c agree
// at every bin EXCEPT Nyquist (f=-0.5 is its own mirror): M_e4[Ny]=e^-8 vs
// M_e1[Ny]=e^-0.5. So modes_mirror[t] = modes_k[t] + dM*F[2048]*(-1)^t.
// Fix: keep 3 inverse FFTs (bands 0,1,2) and synthesize bands 4,3 in the band
// pass via the alternating rank-one correction (F[2048] broadcast from lane 0,
// bit-reversed slot 1). Two ordinal/energy streams for k=1,2; E back to 5
// rows; moments_k = r7's proven 5-band version.

#define NTH 256
#define PHYS(i) ((i) + ((i) >> 4))

typedef _Float16 f16x8 __attribute__((ext_vector_type(8)));
typedef _Float16 f16x2 __attribute__((ext_vector_type(2)));

// ---------------- fused setup: transpose + tables ----------------
__device__ __forceinline__ float mask_f32(int k, int j) {
  // replicate reference: freqs=fftfreq(4096).astype(f32), centers f32, /0.2f, expf
  float f = (float)((j < 2048) ? j : (j - 4096)) * (1.0f / 4096.0f);
  float c = ((float)k - 2.5f) / 5.0f;
  float df = fabsf(f - c);
  float q = df / 0.2f;
  return expf(-0.5f * (q * q));
}

__global__ void setup_k(const float* __restrict__ x, float* __restrict__ xT,
                        float2* __restrict__ Wt, float* __restrict__ Mdr, int n_trans) {
  __shared__ float tile[64][65];
  if ((int)blockIdx.x < n_trans) {
    int bb = blockIdx.x >> 6;
    int tt = blockIdx.x & 63;
    int lane = threadIdx.x & 63;
    int grp = threadIdx.x >> 6;
#pragma unroll
    for (int r = 0; r < 16; ++r) {
      int tl = grp + 4 * r;
      tile[tl][lane] = x[((size_t)bb * 4096 + tt * 64 + tl) * 64 + lane];
    }
    __syncthreads();
#pragma unroll
    for (int r = 0; r < 16; ++r) {
      int dl = grp + 4 * r;
      xT[((size_t)bb * 64 + dl) * 4096 + tt * 64 + lane] = tile[lane][dl];
    }
  } else {
    int j = (blockIdx.x - n_trans) * NTH + threadIdx.x;   // 0..4095
    double ang = -(2.0 * 3.14159265358979323846 / 4096.0) * (double)j;
    double s, c;
    sincos(ang, &s, &c);
    Wt[j] = make_float2((float)c, (float)s);
    int jr = (int)(__brev((unsigned)j) >> 20);            // bitrev12
    int jrn = (4096 - jr) & 4095;
#pragma unroll
    for (int k = 0; k < 3; ++k) {   // bands 0,1,2; 3,4 synthesized via Nyquist fix
      float m1 = mask_f32(k, jr);
      float m2 = mask_f32(k, jrn);
      Mdr[k * 4096 + j] = (float)(((double)m1 + (double)m2) * (0.5 / 4096.0));
    }
  }
}

// ---------------- FFT building blocks (f32) ----------------
template <int S, bool INV>
__device__ __forceinline__ void fft_stage(float* __restrict__ SRe, float* __restrict__ SIm,
                                          const float2* __restrict__ Wt, int tid) {
  const int LOG = 9 - 3 * S;
  const int sub = 1 << LOG;
#pragma unroll
  for (int gi = 0; gi < 2; ++gi) {
    const int g = tid + 256 * gi;
    const int b_hi = g >> LOG;
    const int b_lo = g & (sub - 1);
    const int base = b_hi * (sub << 3) + b_lo;
    int idx[8];
    float ar[8], ai[8];
#pragma unroll
    for (int q = 0; q < 8; ++q) {
      idx[q] = PHYS(base + q * sub);
      ar[q] = SRe[idx[q]];
      ai[q] = SIm[idx[q]];
    }
    float2 t1[4], t2[2], t3;
#pragma unroll
    for (int q = 0; q < 4; ++q) t1[q] = Wt[(b_lo + q * sub) << (3 * S)];
    t2[0] = Wt[b_lo << (3 * S + 1)];
    t2[1] = Wt[(b_lo + sub) << (3 * S + 1)];
    t3 = Wt[b_lo << (3 * S + 2)];
    if (!INV) {
#pragma unroll
      for (int q = 0; q < 4; ++q) {
        float ur = ar[q] - ar[q + 4], ui = ai[q] - ai[q + 4];
        ar[q] += ar[q + 4]; ai[q] += ai[q + 4];
        ar[q + 4] = ur * t1[q].x - ui * t1[q].y;
        ai[q + 4] = ur * t1[q].y + ui * t1[q].x;
      }
#pragma unroll
      for (int h = 0; h < 8; h += 4)
#pragma unroll
        for (int qq = 0; qq < 2; ++qq) {
          int q = h + qq;
          float ur = ar[q] - ar[q + 2], ui = ai[q] - ai[q + 2];
          ar[q] += ar[q + 2]; ai[q] += ai[q + 2];
          ar[q + 2] = ur * t2[qq].x - ui * t2[qq].y;
          ai[q + 2] = ur * t2[qq].y + ui * t2[qq].x;
        }
#pragma unroll
      for (int q = 0; q < 8; q += 2) {
        float ur = ar[q] - ar[q + 1], ui = ai[q] - ai[q + 1];
        ar[q] += ar[q + 1]; ai[q] += ai[q + 1];
        ar[q + 1] = ur * t3.x - ui * t3.y;
        ai[q + 1] = ur * t3.y + ui * t3.x;
      }
    } else {
#pragma unroll
      for (int q = 0; q < 8; q += 2) {
        float br = ar[q + 1] * t3.x + ai[q + 1] * t3.y;
        float bi = ai[q + 1] * t3.x - ar[q + 1] * t3.y;
        ar[q + 1] = ar[q] - br; ai[q + 1] = ai[q] - bi;
        ar[q] += br; ai[q] += bi;
      }
#pragma unroll
      for (int h = 0; h < 8; h += 4)
#pragma unroll
        for (int qq = 0; qq < 2; ++qq) {
          int q = h + qq;
          float br = ar[q + 2] * t2[qq].x + ai[q + 2] * t2[qq].y;
          float bi = ai[q + 2] * t2[qq].x - ar[q + 2] * t2[qq].y;
          ar[q + 2] = ar[q] - br; ai[q + 2] = ai[q] - bi;
          ar[q] += br; ai[q] += bi;
        }
#pragma unroll
      for (int q = 0; q < 4; ++q) {
        float br = ar[q + 4] * t1[q].x + ai[q + 4] * t1[q].y;
        float bi = ai[q + 4] * t1[q].x - ar[q + 4] * t1[q].y;
        ar[q + 4] = ar[q] - br; ai[q + 4] = ai[q] - bi;
        ar[q] += br; ai[q] += bi;
      }
    }
#pragma unroll
    for (int q = 0; q < 8; ++q) { SRe[idx[q]] = ar[q]; SIm[idx[q]] = ai[q]; }
  }
}

__device__ __forceinline__ void s3_fwd(float* ar, float* ai, const float2* __restrict__ Wt) {
  float2 t1[4];
#pragma unroll
  for (int q = 0; q < 4; ++q) t1[q] = Wt[q << 9];
  float2 t20 = Wt[0], t21 = Wt[1 << 10];
#pragma unroll
  for (int q = 0; q < 4; ++q) {
    float ur = ar[q] - ar[q + 4], ui = ai[q] - ai[q + 4];
    ar[q] += ar[q + 4]; ai[q] += ai[q + 4];
    ar[q + 4] = ur * t1[q].x - ui * t1[q].y;
    ai[q + 4] = ur * t1[q].y + ui * t1[q].x;
  }
#pragma unroll
  for (int h = 0; h < 8; h += 4)
#pragma unroll
    for (int qq = 0; qq < 2; ++qq) {
      int q = h + qq;
      float2 t = qq ? t21 : t20;
      float ur = ar[q] - ar[q + 2], ui = ai[q] - ai[q + 2];
      ar[q] += ar[q + 2]; ai[q] += ai[q + 2];
      ar[q + 2] = ur * t.x - ui * t.y;
      ai[q + 2] = ur * t.y + ui * t.x;
    }
#pragma unroll
  for (int q = 0; q < 8; q += 2) {
    float ur = ar[q] - ar[q + 1], ui = ai[q] - ai[q + 1];
    ar[q] += ar[q + 1]; ai[q] += ai[q + 1];
    ar[q + 1] = ur; ai[q + 1] = ui;
  }
}

__device__ __forceinline__ void s3_inv(float* ar, float* ai, const float2* __restrict__ Wt) {
  float2 t1[4];
#pragma unroll
  for (int q = 0; q < 4; ++q) t1[q] = Wt[q << 9];
  float2 t20 = Wt[0], t21 = Wt[1 << 10];
#pragma unroll
  for (int q = 0; q < 8; q += 2) {
    float br = ar[q + 1], bi = ai[q + 1];
    ar[q + 1] = ar[q] - br; ai[q + 1] = ai[q] - bi;
    ar[q] += br; ai[q] += bi;
  }
#pragma unroll
  for (int h = 0; h < 8; h += 4)
#pragma unroll
    for (int qq = 0; qq < 2; ++qq) {
      int q = h + qq;
      float2 t = qq ? t21 : t20;
      float br = ar[q + 2] * t.x + ai[q + 2] * t.y;
      float bi = ai[q + 2] * t.x - ar[q + 2] * t.y;
      ar[q + 2] = ar[q] - br; ai[q + 2] = ai[q] - bi;
      ar[q] += br; ai[q] += bi;
    }
#pragma unroll
  for (int q = 0; q < 4; ++q) {
    float br = ar[q + 4] * t1[q].x + ai[q + 4] * t1[q].y;
    float bi = ai[q + 4] * t1[q].x - ar[q + 4] * t1[q].y;
    ar[q + 4] = ar[q] - br; ai[q + 4] = ai[q] - bi;
    ar[q] += br; ai[q] += bi;
  }
}

__device__ __forceinline__ void corr_write(float* o, const float* st, int j) {
  const int k = (int)((440700928u >> (3 * j)) & 7u);
  const int l = (int)((611428561u >> (3 * j)) & 7u);
  const float Sk = st[k], Sl = st[l];
  const int offk = (k * (11 - k)) >> 1;
  const int offl = (l * (11 - l)) >> 1;
  const float Skl = st[5 + offk + (l - k)];
  const float Skk = st[5 + offk];
  const float Sll = st[5 + offl];
  const float invT = 1.0f / 4096.0f;
  float cov = Skl - Sk * Sl * invT;
  float vk = Skk - Sk * Sk * invT;
  float vl = Sll - Sl * Sl * invT;
  float dk = sqrtf(fmaxf(vk, 0.f)), dl = sqrtf(fmaxf(vl, 0.f));
  float den = dk * dl;
  float corr = den > 0.f ? cov / den : 0.f;
  o[36 + j] = fminf(1.f, fmaxf(-1.f, corr));
}

// ---------------- kernel 1: 3 FFTs + 5 ordinal/energy streams ----------------
__global__ void __launch_bounds__(NTH, 2)
tf_main(const float* __restrict__ x,
        const float* __restrict__ xT, int use_xt,
        const float2* __restrict__ Wt,
        const float* __restrict__ Mdr,
        _Float16* __restrict__ E,
        float* __restrict__ out) {
  __shared__ float SRe[4352];
  __shared__ float SIm[4352];
  __shared__ unsigned char hist[NTH * 76];
  __shared__ float fnyb[2];   // broadcast of F_z[2048] (Re, Im)

  const int tid = threadIdx.x;
  const int beta = blockIdx.x;
  const int b = beta >> 5;
  const int dA = (beta & 31) * 2;

  {  // zero own hist slice (76 B, dword-aligned)
    unsigned int* hw = (unsigned int*)(hist + tid * 76);
#pragma unroll
    for (int i = 0; i < 19; ++i) hw[i] = 0u;
  }

  // ---- stage x (two series -> complex) ----
  if (use_xt) {
    const float4* ra = (const float4*)(xT + (size_t)(b * 64 + dA) * 4096);
    const float4* rb = (const float4*)(xT + (size_t)(b * 64 + dA + 1) * 4096);
    for (int t4 = tid; t4 < 1024; t4 += NTH) {
      float4 va = ra[t4], vb = rb[t4];
      int t = t4 * 4;
      SRe[PHYS(t)] = va.x;     SIm[PHYS(t)] = vb.x;
      SRe[PHYS(t + 1)] = va.y; SIm[PHYS(t + 1)] = vb.y;
      SRe[PHYS(t + 2)] = va.z; SIm[PHYS(t + 2)] = vb.z;
      SRe[PHYS(t + 3)] = va.w; SIm[PHYS(t + 3)] = vb.w;
    }
  } else {
    const float2* xp = (const float2*)(x + (size_t)b * 4096 * 64 + dA);
    for (int t = tid; t < 4096; t += NTH) {
      float2 v = xp[(size_t)t * 32];
      SRe[PHYS(t)] = v.x;
      SIm[PHYS(t)] = v.y;
    }
  }
  __syncthreads();

  // ---- forward FFT: stages s=0..2 in LDS, s=3 in regs ----
  fft_stage<0, false>(SRe, SIm, Wt, tid); __syncthreads();
  fft_stage<1, false>(SRe, SIm, Wt, tid); __syncthreads();
  fft_stage<2, false>(SRe, SIm, Wt, tid); __syncthreads();

  float Fr[16], Fi[16];
#pragma unroll
  for (int j = 0; j < 16; ++j) {
    int p = PHYS(tid * 16 + j);
    Fr[j] = SRe[p]; Fi[j] = SIm[p];
  }
  s3_fwd(&Fr[0], &Fi[0], Wt);
  s3_fwd(&Fr[8], &Fi[8], Wt);
  // Fr/Fi hold spectrum at bit-reversed slots; bitrev12(1)=2048 -> F_Ny = lane0 slot1
  if (tid == 0) { fnyb[0] = Fr[1]; fnyb[1] = Fi[1]; }

#pragma unroll
  for (int k = 0; k < 3; ++k) {
    __syncthreads();  // previous band's readers done; also publishes fnyb
#pragma unroll
    for (int h = 0; h < 2; ++h) {   // 8-element halves: low live regs
      float Zr[8], Zi[8];
#pragma unroll
      for (int j = 0; j < 8; ++j) {
        float m = Mdr[k * 4096 + tid * 16 + h * 8 + j];
        Zr[j] = Fr[h * 8 + j] * m; Zi[j] = Fi[h * 8 + j] * m;
      }
      s3_inv(Zr, Zi, Wt);
#pragma unroll
      for (int j = 0; j < 8; ++j) {
        int p = PHYS(tid * 16 + h * 8 + j);
        SRe[p] = Zr[j]; SIm[p] = Zi[j];
      }
    }
    __syncthreads();
    fft_stage<2, true>(SRe, SIm, Wt, tid); __syncthreads();
    fft_stage<1, true>(SRe, SIm, Wt, tid); __syncthreads();
    fft_stage<0, true>(SRe, SIm, Wt, tid); __syncthreads();
    // SRe[t] = modes_a[t] (band k), SIm[t] = modes_b[t], natural order

    // ---- band pass: plain stream (band k) + corrected stream (mirror band) ----
    {
      const int t0 = tid * 16;
      float a0 = SRe[PHYS(t0)], a1 = SRe[PHYS(t0 + 1)];
      float c0 = SIm[PHYS(t0)], c1 = SIm[PHYS(t0 + 1)];
      alignas(16) _Float16 ehA[16], ehB[16];
      ehA[0] = (_Float16)(a0 * a0); ehA[1] = (_Float16)(a1 * a1);
      ehB[0] = (_Float16)(c0 * c0); ehB[1] = (_Float16)(c1 * c1);
      int pa = 0, pb = 0;
      unsigned char* myh = hist + tid * 76;

      // mirror-band correction: modes_mirror[t] = modes_k[t] + dM*F_Ny*(-1)^t
      float da = 0.f, db = 0.f;
      alignas(16) _Float16 ehA2[16], ehB2[16];
      float aq0 = 0.f, aq1 = 0.f, cq0 = 0.f, cq1 = 0.f;
      int pa2 = 0, pb2 = 0;
      if (k >= 1) {
        float m_mir = mask_f32(5 - k, 2048);   // k=1 -> band4, k=2 -> band3
        float m_own = mask_f32(k, 2048);
        float dM = (float)(((double)m_mir - (double)m_own) * (1.0 / 4096.0));
        da = dM * fnyb[0];
        db = dM * fnyb[1];
        aq0 = a0 + da; aq1 = a1 - da;      // t0 even -> sigma=+1 at t0
        cq0 = c0 + db; cq1 = c1 - db;
        ehA2[0] = (_Float16)(aq0 * aq0); ehA2[1] = (_Float16)(aq1 * aq1);
        ehB2[0] = (_Float16)(cq0 * cq0); ehB2[1] = (_Float16)(cq1 * cq1);
      }

#pragma unroll
      for (int step = 0; step <= 16; ++step) {
        const int w = t0 + step;
        if (w < 4094) {
          float a2 = SRe[PHYS(w + 2)];
          float c2 = SIm[PHYS(w + 2)];
          if (step <= 13) {
            ehA[step + 2] = (_Float16)(a2 * a2);
            ehB[step + 2] = (_Float16)(c2 * c2);
          }
          int ia = (int)(a0 <= a1) | ((int)(a0 <= a2) << 1) | ((int)(a1 <= a2) << 2);
          int ca = (int)((537125u >> (3 * ia)) & 7u);
          int ib = (int)(c0 <= c1) | ((int)(c0 <= c2) << 1) | ((int)(c1 <= c2) << 2);
          int cb = (int)((537125u >> (3 * ib)) & 7u);
          if (step >= 1) { myh[pa * 6 + ca] += 1; myh[36 + pb * 6 + cb] += 1; }
          pa = ca; pb = cb;
          a0 = a1; a1 = a2;
          c0 = c1; c1 = c2;

          if (k >= 1) {
            // sigma at time w+2 = (-1)^(t0+step) = (-1)^step  (t0 even)
            const float sda = (step & 1) ? -da : da;
            const float sdb = (step & 1) ? -db : db;
            float aq2 = a2 + sda;   // note: a2 still holds modes at w+2
            float cq2 = c2 + sdb;
            if (step <= 13) {
              ehA2[step + 2] = (_Float16)(aq2 * aq2);
              ehB2[step + 2] = (_Float16)(cq2 * cq2);
            }
            int ia2 = (int)(aq0 <= aq1) | ((int)(aq0 <= aq2) << 1) | ((int)(aq1 <= aq2) << 2);
            int ca2 = (int)((537125u >> (3 * ia2)) & 7u);
            int ib2 = (int)(cq0 <= cq1) | ((int)(cq0 <= cq2) << 1) | ((int)(cq1 <= cq2) << 2);
            int cb2 = (int)((537125u >> (3 * ib2)) & 7u);
            if (step >= 1) { myh[pa2 * 6 + ca2] += 1; myh[36 + pb2 * 6 + cb2] += 1; }
            pa2 = ca2; pb2 = cb2;
            aq0 = aq1; aq1 = aq2;
            cq0 = cq1; cq1 = cq2;
          }
        }
      }
      // coalesced f16 stores: plain band -> row k; mirror band -> row 5-k
      f16x8* EA = (f16x8*)(E + ((size_t)(b * 64 + dA) * 5 + k) * 4096 + t0);
      f16x8* EB = (f16x8*)(E + ((size_t)(b * 64 + dA + 1) * 5 + k) * 4096 + t0);
      EA[0] = *(const f16x8*)&ehA[0]; EA[1] = *(const f16x8*)&ehA[8];
      EB[0] = *(const f16x8*)&ehB[0]; EB[1] = *(const f16x8*)&ehB[8];
      if (k >= 1) {
        const int mr = 5 - k;
        f16x8* EA2 = (f16x8*)(E + ((size_t)(b * 64 + dA) * 5 + mr) * 4096 + t0);
        f16x8* EB2 = (f16x8*)(E + ((size_t)(b * 64 + dA + 1) * 5 + mr) * 4096 + t0);
        EA2[0] = *(const f16x8*)&ehA2[0]; EA2[1] = *(const f16x8*)&ehA2[8];
        EB2[0] = *(const f16x8*)&ehB2[0]; EB2[1] = *(const f16x8*)&ehB2[8];
      }
    }
  }
  __syncthreads();   // all band-pass LDS reads done -> SRe reusable

  // ---- histogram reduce + tmptm outputs ----
  unsigned int* histf = (unsigned int*)SRe;  // 72
  float* rowinv = SIm;                       // 12
  if (tid < 72) {
    unsigned int s = 0;
    for (int i = 0; i < 256; ++i) s += (unsigned int)hist[i * 76 + tid];
    histf[tid] = s;
  }
  __syncthreads();
  if (tid < 12) {
    int base0 = (tid < 6 ? 0 : 36) + (tid % 6) * 6;
    float rs = (float)(histf[base0] + histf[base0 + 1] + histf[base0 + 2] +
                       histf[base0 + 3] + histf[base0 + 4] + histf[base0 + 5]);
    rowinv[tid] = rs > 0.f ? 1.0f / rs : 1.0f;
  }
  __syncthreads();

  float* oA = out + (size_t)(b * 64 + dA) * 46;
  float* oB = oA + 46;
  if (tid < 36) oA[tid] = (float)histf[tid] * rowinv[tid / 6];
  if (tid >= 64 && tid < 100) {
    int j = tid - 64;
    oB[j] = (float)histf[36 + j] * rowinv[6 + j / 6];
  }
}

// ---------------- kernel 2: stream energies -> 20 moments -> corr ----------------
__global__ void __launch_bounds__(NTH)
moments_k(const _Float16* __restrict__ E, float* __restrict__ out) {
  __shared__ float red[4][20];
  __shared__ float stats[20];
  const int bd = blockIdx.x;
  const int tid = threadIdx.x;
  const f16x2* Eb = (const f16x2*)(E + (size_t)bd * 5 * 4096);

  float acc[20];
#pragma unroll
  for (int j = 0; j < 20; ++j) acc[j] = 0.f;
  for (int i = 0; i < 8; ++i) {
    int t2 = tid + 256 * i;              // half2 index, 0..2047 (coalesced)
    float ex[5], ey[5];
#pragma unroll
    for (int k = 0; k < 5; ++k) {
      f16x2 v = Eb[k * 2048 + t2];
      ex[k] = (float)v.x; ey[k] = (float)v.y;
    }
    int id5 = 5;
#pragma unroll
    for (int k = 0; k < 5; ++k) {
      acc[k] += ex[k] + ey[k];
#pragma unroll
      for (int l = k; l < 5; ++l) {
        acc[id5] += ex[k] * ex[l] + ey[k] * ey[l];
        ++id5;
      }
    }
  }
  const int lane = tid & 63, wv = tid >> 6;
#pragma unroll
  for (int j = 0; j < 20; ++j) {
    float v = acc[j];
    v += __shfl_down(v, 32, 64);
    v += __shfl_down(v, 16, 64);
    v += __shfl_down(v, 8, 64);
    v += __shfl_down(v, 4, 64);
    v += __shfl_down(v, 2, 64);
    v += __shfl_down(v, 1, 64);
    if (lane == 0) red[wv][j] = v;
  }
  __syncthreads();
  if (tid < 20) stats[tid] = red[0][tid] + red[1][tid] + red[2][tid] + red[3][tid];
  __syncthreads();
  if (tid < 10) corr_write(out + (size_t)bd * 46, stats, tid);
}

// ---------------- launch ----------------
extern "C" void kernel_launch(void* const* d_in, const int* in_sizes, int n_in,
                              void* d_out, int out_size, void* d_ws, size_t ws_size,
                              hipStream_t stream) {
  (void)in_sizes; (void)n_in; (void)out_size;
  const float* x = (const float*)d_in[0];
  float* out = (float*)d_out;
  char* ws = (char*)d_ws;

  float2* Wt = (float2*)ws;                      // 32 KB
  float* Mdr = (float*)(ws + 32768);             // 48 KB (3 bands)
  _Float16* E = (_Float16*)(ws + 131072);        // 1024*5*4096*2 = 41.94 MB
  const size_t E_end = 131072 + (size_t)1024 * 5 * 4096 * 2;
  float* xT = (float*)(ws + E_end);              // 16.78 MB (optional)
  int use_xt = (ws_size >= E_end + (size_t)16 * 64 * 4096 * 4) ? 1 : 0;
  int n_trans = use_xt ? 1024 : 0;

  setup_k<<<n_trans + 16, NTH, 0, stream>>>(x, xT, Wt, Mdr, n_trans);
  tf_main<<<512, NTH, 0, stream>>>(x, xT, use_xt, Wt, Mdr, E, out);
  moments_k<<<1024, NTH, 0, stream>>>(E, out);
}

// Round 11
// 116.539 us; speedup vs baseline: 2.1785x; 1.0429x over previous
//
#include <hip/hip_runtime.h>
#include <math.h>

// Fully-fused single-pass pipeline (E buffer + moments_k deleted).
// Key enabler: with the 3-band symmetric structure (r10), all 5 band energies
// at time t are computable during band-2's pass from (a) retained f16 modes of
// bands 0,1 -- only 2 bands x 16 t x 2 series = 32 VGPRs, allocatable under
// the proven launch_bounds(256,2) cap, unlike the original 160-reg stash --
// (b) live band-2 f32 modes in LDS, (c) the Nyquist deltas d3,d4
// (modes_mirror[t] = modes_k[t] + dM*F_Ny*(-1)^t, r10-proven).
// Moments accumulate in-register in the band-2 pass; 40-way shuffle reduce
// (r2-proven epilogue); corr written in-kernel. Removes 41 MB E-write,
// 42 MB moments read, and one launch.

#define NTH 256
#define PHYS(i) ((i) + ((i) >> 4))

typedef _Float16 f16x2 __attribute__((ext_vector_type(2)));

__device__ __forceinline__ void rset(f16x2* r, int j, float v) {
  if (j & 1) r[j >> 1].y = (_Float16)v;
  else       r[j >> 1].x = (_Float16)v;
}
__device__ __forceinline__ float rget(const f16x2* r, int j) {
  return (j & 1) ? (float)r[j >> 1].y : (float)r[j >> 1].x;
}

// accumulate 5 band energies + upper-triangular products into acc[20]
__device__ __forceinline__ void madd5(float* acc, float m0, float m1, float m2,
                                      float m3, float m4) {
  float e[5];
  e[0] = m0 * m0; e[1] = m1 * m1; e[2] = m2 * m2; e[3] = m3 * m3; e[4] = m4 * m4;
  int id = 5;
#pragma unroll
  for (int a = 0; a < 5; ++a) {
    acc[a] += e[a];
#pragma unroll
    for (int l = a; l < 5; ++l) { acc[id] += e[a] * e[l]; ++id; }
  }
}

// ---------------- fused setup: transpose + tables ----------------
__device__ __forceinline__ float mask_f32(int k, int j) {
  // replicate reference: freqs=fftfreq(4096).astype(f32), centers f32, /0.2f, expf
  float f = (float)((j < 2048) ? j : (j - 4096)) * (1.0f / 4096.0f);
  float c = ((float)k - 2.5f) / 5.0f;
  float df = fabsf(f - c);
  float q = df / 0.2f;
  return expf(-0.5f * (q * q));
}

__global__ void setup_k(const float* __restrict__ x, float* __restrict__ xT,
                        float2* __restrict__ Wt, float* __restrict__ Mdr, int n_trans) {
  __shared__ float tile[64][65];
  if ((int)blockIdx.x < n_trans) {
    int bb = blockIdx.x >> 6;
    int tt = blockIdx.x & 63;
    int lane = threadIdx.x & 63;
    int grp = threadIdx.x >> 6;
#pragma unroll
    for (int r = 0; r < 16; ++r) {
      int tl = grp + 4 * r;
      tile[tl][lane] = x[((size_t)bb * 4096 + tt * 64 + tl) * 64 + lane];
    }
    __syncthreads();
#pragma unroll
    for (int r = 0; r < 16; ++r) {
      int dl = grp + 4 * r;
      xT[((size_t)bb * 64 + dl) * 4096 + tt * 64 + lane] = tile[lane][dl];
    }
  } else {
    int j = (blockIdx.x - n_trans) * NTH + threadIdx.x;   // 0..4095
    double ang = -(2.0 * 3.14159265358979323846 / 4096.0) * (double)j;
    double s, c;
    sincos(ang, &s, &c);
    Wt[j] = make_float2((float)c, (float)s);
    int jr = (int)(__brev((unsigned)j) >> 20);            // bitrev12
    int jrn = (4096 - jr) & 4095;
#pragma unroll
    for (int k = 0; k < 3; ++k) {   // bands 0,1,2; 3,4 via Nyquist correction
      float m1 = mask_f32(k, jr);
      float m2 = mask_f32(k, jrn);
      Mdr[k * 4096 + j] = (float)(((double)m1 + (double)m2) * (0.5 / 4096.0));
    }
  }
}

// ---------------- FFT building blocks (f32) ----------------
template <int S, bool INV>
__device__ __forceinline__ void fft_stage(float* __restrict__ SRe, float* __restrict__ SIm,
                                          const float2* __restrict__ Wt, int tid) {
  const int LOG = 9 - 3 * S;
  const int sub = 1 << LOG;
#pragma unroll
  for (int gi = 0; gi < 2; ++gi) {
    const int g = tid + 256 * gi;
    const int b_hi = g >> LOG;
    const int b_lo = g & (sub - 1);
    const int base = b_hi * (sub << 3) + b_lo;
    int idx[8];
    float ar[8], ai[8];
#pragma unroll
    for (int q = 0; q < 8; ++q) {
      idx[q] = PHYS(base + q * sub);
      ar[q] = SRe[idx[q]];
      ai[q] = SIm[idx[q]];
    }
    float2 t1[4], t2[2], t3;
#pragma unroll
    for (int q = 0; q < 4; ++q) t1[q] = Wt[(b_lo + q * sub) << (3 * S)];
    t2[0] = Wt[b_lo << (3 * S + 1)];
    t2[1] = Wt[(b_lo + sub) << (3 * S + 1)];
    t3 = Wt[b_lo << (3 * S + 2)];
    if (!INV) {
#pragma unroll
      for (int q = 0; q < 4; ++q) {
        float ur = ar[q] - ar[q + 4], ui = ai[q] - ai[q + 4];
        ar[q] += ar[q + 4]; ai[q] += ai[q + 4];
        ar[q + 4] = ur * t1[q].x - ui * t1[q].y;
        ai[q + 4] = ur * t1[q].y + ui * t1[q].x;
      }
#pragma unroll
      for (int h = 0; h < 8; h += 4)
#pragma unroll
        for (int qq = 0; qq < 2; ++qq) {
          int q = h + qq;
          float ur = ar[q] - ar[q + 2], ui = ai[q] - ai[q + 2];
          ar[q] += ar[q + 2]; ai[q] += ai[q + 2];
          ar[q + 2] = ur * t2[qq].x - ui * t2[qq].y;
          ai[q + 2] = ur * t2[qq].y + ui * t2[qq].x;
        }
#pragma unroll
      for (int q = 0; q < 8; q += 2) {
        float ur = ar[q] - ar[q + 1], ui = ai[q] - ai[q + 1];
        ar[q] += ar[q + 1]; ai[q] += ai[q + 1];
        ar[q + 1] = ur * t3.x - ui * t3.y;
        ai[q + 1] = ur * t3.y + ui * t3.x;
      }
    } else {
#pragma unroll
      for (int q = 0; q < 8; q += 2) {
        float br = ar[q + 1] * t3.x + ai[q + 1] * t3.y;
        float bi = ai[q + 1] * t3.x - ar[q + 1] * t3.y;
        ar[q + 1] = ar[q] - br; ai[q + 1] = ai[q] - bi;
        ar[q] += br; ai[q] += bi;
      }
#pragma unroll
      for (int h = 0; h < 8; h += 4)
#pragma unroll
        for (int qq = 0; qq < 2; ++qq) {
          int q = h + qq;
          float br = ar[q + 2] * t2[qq].x + ai[q + 2] * t2[qq].y;
          float bi = ai[q + 2] * t2[qq].x - ar[q + 2] * t2[qq].y;
          ar[q + 2] = ar[q] - br; ai[q + 2] = ai[q] - bi;
          ar[q] += br; ai[q] += bi;
        }
#pragma unroll
      for (int q = 0; q < 4; ++q) {
        float br = ar[q + 4] * t1[q].x + ai[q + 4] * t1[q].y;
        float bi = ai[q + 4] * t1[q].x - ar[q + 4] * t1[q].y;
        ar[q + 4] = ar[q] - br; ai[q + 4] = ai[q] - bi;
        ar[q] += br; ai[q] += bi;
      }
    }
#pragma unroll
    for (int q = 0; q < 8; ++q) { SRe[idx[q]] = ar[q]; SIm[idx[q]] = ai[q]; }
  }
}

__device__ __forceinline__ void s3_fwd(float* ar, float* ai, const float2* __restrict__ Wt) {
  float2 t1[4];
#pragma unroll
  for (int q = 0; q < 4; ++q) t1[q] = Wt[q << 9];
  float2 t20 = Wt[0], t21 = Wt[1 << 10];
#pragma unroll
  for (int q = 0; q < 4; ++q) {
    float ur = ar[q] - ar[q + 4], ui = ai[q] - ai[q + 4];
    ar[q] += ar[q + 4]; ai[q] += ai[q + 4];
    ar[q + 4] = ur * t1[q].x - ui * t1[q].y;
    ai[q + 4] = ur * t1[q].y + ui * t1[q].x;
  }
#pragma unroll
  for (int h = 0; h < 8; h += 4)
#pragma unroll
    for (int qq = 0; qq < 2; ++qq) {
      int q = h + qq;
      float2 t = qq ? t21 : t20;
      float ur = ar[q] - ar[q + 2], ui = ai[q] - ai[q + 2];
      ar[q] += ar[q + 2]; ai[q] += ai[q + 2];
      ar[q + 2] = ur * t.x - ui * t.y;
      ai[q + 2] = ur * t.y + ui * t.x;
    }
#pragma unroll
  for (int q = 0; q < 8; q += 2) {
    float ur = ar[q] - ar[q + 1], ui = ai[q] - ai[q + 1];
    ar[q] += ar[q + 1]; ai[q] += ai[q + 1];
    ar[q + 1] = ur; ai[q + 1] = ui;
  }
}

__device__ __forceinline__ void s3_inv(float* ar, float* ai, const float2* __restrict__ Wt) {
  float2 t1[4];
#pragma unroll
  for (int q = 0; q < 4; ++q) t1[q] = Wt[q << 9];
  float2 t20 = Wt[0], t21 = Wt[1 << 10];
#pragma unroll
  for (int q = 0; q < 8; q += 2) {
    float br = ar[q + 1], bi = ai[q + 1];
    ar[q + 1] = ar[q] - br; ai[q + 1] = ai[q] - bi;
    ar[q] += br; ai[q] += bi;
  }
#pragma unroll
  for (int h = 0; h < 8; h += 4)
#pragma unroll
    for (int qq = 0; qq < 2; ++qq) {
      int q = h + qq;
      float2 t = qq ? t21 : t20;
      float br = ar[q + 2] * t.x + ai[q + 2] * t.y;
      float bi = ai[q + 2] * t.x - ar[q + 2] * t.y;
      ar[q + 2] = ar[q] - br; ai[q + 2] = ai[q] - bi;
      ar[q] += br; ai[q] += bi;
    }
#pragma unroll
  for (int q = 0; q < 4; ++q) {
    float br = ar[q + 4] * t1[q].x + ai[q + 4] * t1[q].y;
    float bi = ai[q + 4] * t1[q].x - ar[q + 4] * t1[q].y;
    ar[q + 4] = ar[q] - br; ai[q + 4] = ai[q] - bi;
    ar[q] += br; ai[q] += bi;
  }
}

__device__ __forceinline__ void corr_write(float* o, const float* st, int j) {
  const int k = (int)((440700928u >> (3 * j)) & 7u);
  const int l = (int)((611428561u >> (3 * j)) & 7u);
  const float Sk = st[k], Sl = st[l];
  const int offk = (k * (11 - k)) >> 1;
  const int offl = (l * (11 - l)) >> 1;
  const float Skl = st[5 + offk + (l - k)];
  const float Skk = st[5 + offk];
  const float Sll = st[5 + offl];
  const float invT = 1.0f / 4096.0f;
  float cov = Skl - Sk * Sl * invT;
  float vk = Skk - Sk * Sk * invT;
  float vl = Sll - Sl * Sl * invT;
  float dk = sqrtf(fmaxf(vk, 0.f)), dl = sqrtf(fmaxf(vl, 0.f));
  float den = dk * dl;
  float corr = den > 0.f ? cov / den : 0.f;
  o[36 + j] = fminf(1.f, fmaxf(-1.f, corr));
}

// ---------------- the one main kernel ----------------
__global__ void __launch_bounds__(NTH, 2)
tf_main(const float* __restrict__ x,
        const float* __restrict__ xT, int use_xt,
        const float2* __restrict__ Wt,
        const float* __restrict__ Mdr,
        float* __restrict__ out) {
  __shared__ float SRe[4352];
  __shared__ float SIm[4352];
  __shared__ unsigned char hist[NTH * 76];
  __shared__ float fnyb[2];   // broadcast of F_z[2048] (Re, Im)

  const int tid = threadIdx.x;
  const int beta = blockIdx.x;
  const int b = beta >> 5;
  const int dA = (beta & 31) * 2;

  {  // zero own hist slice
    unsigned int* hw = (unsigned int*)(hist + tid * 76);
#pragma unroll
    for (int i = 0; i < 19; ++i) hw[i] = 0u;
  }

  // ---- stage x (two series -> complex) ----
  if (use_xt) {
    const float4* ra = (const float4*)(xT + (size_t)(b * 64 + dA) * 4096);
    const float4* rb = (const float4*)(xT + (size_t)(b * 64 + dA + 1) * 4096);
    for (int t4 = tid; t4 < 1024; t4 += NTH) {
      float4 va = ra[t4], vb = rb[t4];
      int t = t4 * 4;
      SRe[PHYS(t)] = va.x;     SIm[PHYS(t)] = vb.x;
      SRe[PHYS(t + 1)] = va.y; SIm[PHYS(t + 1)] = vb.y;
      SRe[PHYS(t + 2)] = va.z; SIm[PHYS(t + 2)] = vb.z;
      SRe[PHYS(t + 3)] = va.w; SIm[PHYS(t + 3)] = vb.w;
    }
  } else {
    const float2* xp = (const float2*)(x + (size_t)b * 4096 * 64 + dA);
    for (int t = tid; t < 4096; t += NTH) {
      float2 v = xp[(size_t)t * 32];
      SRe[PHYS(t)] = v.x;
      SIm[PHYS(t)] = v.y;
    }
  }
  __syncthreads();

  // ---- forward FFT: stages s=0..2 in LDS, s=3 in regs ----
  fft_stage<0, false>(SRe, SIm, Wt, tid); __syncthreads();
  fft_stage<1, false>(SRe, SIm, Wt, tid); __syncthreads();
  fft_stage<2, false>(SRe, SIm, Wt, tid); __syncthreads();

  float Fr[16], Fi[16];
#pragma unroll
  for (int j = 0; j < 16; ++j) {
    int p = PHYS(tid * 16 + j);
    Fr[j] = SRe[p]; Fi[j] = SIm[p];
  }
  s3_fwd(&Fr[0], &Fi[0], Wt);
  s3_fwd(&Fr[8], &Fi[8], Wt);
  // bitrev12(1)=2048 -> F_Ny = lane0 slot1
  if (tid == 0) { fnyb[0] = Fr[1]; fnyb[1] = Fi[1]; }

  // retained f16 modes of bands 0,1 (32 VGPRs) + moment accumulators
  f16x2 rA0[8], rB0[8], rA1[8], rB1[8];
  float d4a = 0.f, d4b = 0.f;
  float accA[20], accB[20];

#pragma unroll
  for (int k = 0; k < 3; ++k) {
    __syncthreads();  // previous band's readers done; also publishes fnyb
#pragma unroll
    for (int h = 0; h < 2; ++h) {
      float Zr[8], Zi[8];
#pragma unroll
      for (int j = 0; j < 8; ++j) {
        float m = Mdr[k * 4096 + tid * 16 + h * 8 + j];
        Zr[j] = Fr[h * 8 + j] * m; Zi[j] = Fi[h * 8 + j] * m;
      }
      s3_inv(Zr, Zi, Wt);
#pragma unroll
      for (int j = 0; j < 8; ++j) {
        int p = PHYS(tid * 16 + h * 8 + j);
        SRe[p] = Zr[j]; SIm[p] = Zi[j];
      }
    }
    __syncthreads();
    fft_stage<2, true>(SRe, SIm, Wt, tid); __syncthreads();
    fft_stage<1, true>(SRe, SIm, Wt, tid); __syncthreads();
    fft_stage<0, true>(SRe, SIm, Wt, tid); __syncthreads();
    // SRe[t] = modes_a[t] (band k), SIm[t] = modes_b[t], natural order

    // ---- band pass ----
    {
      const int t0 = tid * 16;
      float a0 = SRe[PHYS(t0)], a1 = SRe[PHYS(t0 + 1)];
      float c0 = SIm[PHYS(t0)], c1 = SIm[PHYS(t0 + 1)];
      int pa = 0, pb = 0;
      unsigned char* myh = hist + tid * 76;

      // mirror-band Nyquist correction constants
      float da = 0.f, db = 0.f;
      float aq0 = 0.f, aq1 = 0.f, cq0 = 0.f, cq1 = 0.f;
      int pa2 = 0, pb2 = 0;
      if (k >= 1) {
        float m_mir = mask_f32(5 - k, 2048);   // k=1 -> band4, k=2 -> band3
        float m_own = mask_f32(k, 2048);
        float dM = (float)(((double)m_mir - (double)m_own) * (1.0 / 4096.0));
        da = dM * fnyb[0];
        db = dM * fnyb[1];
        aq0 = a0 + da; aq1 = a1 - da;      // t0 even -> sigma=+1 at t0
        cq0 = c0 + db; cq1 = c1 - db;
      }
      if (k == 1) { d4a = da; d4b = db; }

      // prologue j = 0,1
      if (k == 0) {
        rset(rA0, 0, a0); rset(rA0, 1, a1);
        rset(rB0, 0, c0); rset(rB0, 1, c1);
      } else if (k == 1) {
        rset(rA1, 0, a0); rset(rA1, 1, a1);
        rset(rB1, 0, c0); rset(rB1, 1, c1);
      } else {
#pragma unroll
        for (int j = 0; j < 20; ++j) { accA[j] = 0.f; accB[j] = 0.f; }
        madd5(accA, rget(rA0, 0), rget(rA1, 0), a0, a0 + da, rget(rA1, 0) + d4a);
        madd5(accB, rget(rB0, 0), rget(rB1, 0), c0, c0 + db, rget(rB1, 0) + d4b);
        madd5(accA, rget(rA0, 1), rget(rA1, 1), a1, a1 - da, rget(rA1, 1) - d4a);
        madd5(accB, rget(rB0, 1), rget(rB1, 1), c1, c1 - db, rget(rB1, 1) - d4b);
      }

#pragma unroll
      for (int step = 0; step <= 16; ++step) {
        const int w = t0 + step;
        if (w < 4094) {
          float a2 = SRe[PHYS(w + 2)];
          float c2 = SIm[PHYS(w + 2)];
          const float sg = (step & 1) ? -1.f : 1.f;   // sigma at t = t0+step+2... note below
          if (step <= 13) {
            const int j = step + 2;                   // parity of j == parity of step
            if (k == 0) {
              rset(rA0, j, a2); rset(rB0, j, c2);
            } else if (k == 1) {
              rset(rA1, j, a2); rset(rB1, j, c2);
            } else {
              madd5(accA, rget(rA0, j), rget(rA1, j), a2, a2 + sg * da, rget(rA1, j) + sg * d4a);
              madd5(accB, rget(rB0, j), rget(rB1, j), c2, c2 + sg * db, rget(rB1, j) + sg * d4b);
            }
          }
          int ia = (int)(a0 <= a1) | ((int)(a0 <= a2) << 1) | ((int)(a1 <= a2) << 2);
          int ca = (int)((537125u >> (3 * ia)) & 7u);
          int ib = (int)(c0 <= c1) | ((int)(c0 <= c2) << 1) | ((int)(c1 <= c2) << 2);
          int cb = (int)((537125u >> (3 * ib)) & 7u);
          if (step >= 1) { myh[pa * 6 + ca] += 1; myh[36 + pb * 6 + cb] += 1; }
          pa = ca; pb = cb;
          a0 = a1; a1 = a2;
          c0 = c1; c1 = c2;

          if (k >= 1) {
            const float sda = sg * da;
            const float sdb = sg * db;
            float aq2 = a2 + sda;
            float cq2 = c2 + sdb;
            int ia2 = (int)(aq0 <= aq1) | ((int)(aq0 <= aq2) << 1) | ((int)(aq1 <= aq2) << 2);
            int ca2 = (int)((537125u >> (3 * ia2)) & 7u);
            int ib2 = (int)(cq0 <= cq1) | ((int)(cq0 <= cq2) << 1) | ((int)(cq1 <= cq2) << 2);
            int cb2 = (int)((537125u >> (3 * ib2)) & 7u);
            if (step >= 1) { myh[pa2 * 6 + ca2] += 1; myh[36 + pb2 * 6 + cb2] += 1; }
            pa2 = ca2; pb2 = cb2;
            aq0 = aq1; aq1 = aq2;
            cq0 = cq1; cq1 = cq2;
          }
        }
      }
    }
  }
  __syncthreads();   // all band-pass LDS reads done -> SRe/SIm reusable

  // epilogue scratch overlaid on FFT buffers
  float* red = SIm;                          // [4][40]
  float* stats = SIm + 160;                  // 40
  float* rowinv = SIm + 200;                 // 12
  unsigned int* histf = (unsigned int*)SRe;  // 72

  // ---- 40-way moment block reduce ----
  const int lane = tid & 63, wv = tid >> 6;
#pragma unroll
  for (int j = 0; j < 40; ++j) {
    float v = (j < 20) ? accA[j] : accB[j - 20];
    v += __shfl_down(v, 32, 64);
    v += __shfl_down(v, 16, 64);
    v += __shfl_down(v, 8, 64);
    v += __shfl_down(v, 4, 64);
    v += __shfl_down(v, 2, 64);
    v += __shfl_down(v, 1, 64);
    if (lane == 0) red[wv * 40 + j] = v;
  }
  __syncthreads();
  if (tid < 40) stats[tid] = red[tid] + red[40 + tid] + red[80 + tid] + red[120 + tid];
  if (tid < 72) {
    unsigned int s = 0;
    for (int i = 0; i < 256; ++i) s += (unsigned int)hist[i * 76 + tid];
    histf[tid] = s;
  }
  __syncthreads();
  if (tid < 12) {
    int base0 = (tid < 6 ? 0 : 36) + (tid % 6) * 6;
    float rs = (float)(histf[base0] + histf[base0 + 1] + histf[base0 + 2] +
                       histf[base0 + 3] + histf[base0 + 4] + histf[base0 + 5]);
    rowinv[tid] = rs > 0.f ? 1.0f / rs : 1.0f;
  }
  __syncthreads();

  float* oA = out + (size_t)(b * 64 + dA) * 46;
  float* oB = oA + 46;
  if (tid < 36) oA[tid] = (float)histf[tid] * rowinv[tid / 6];
  if (tid >= 64 && tid < 100) {
    int j = tid - 64;
    oB[j] = (float)histf[36 + j] * rowinv[6 + j / 6];
  }
  if (tid >= 128 && tid < 138) corr_write(oA, stats, tid - 128);
  if (tid >= 160 && tid < 170) corr_write(oB, stats + 20, tid - 160);
}

// ---------------- launch ----------------
extern "C" void kernel_launch(void* const* d_in, const int* in_sizes, int n_in,
                              void* d_out, int out_size, void* d_ws, size_t ws_size,
                              hipStream_t stream) {
  (void)in_sizes; (void)n_in; (void)out_size;
  const float* x = (const float*)d_in[0];
  float* out = (float*)d_out;
  char* ws = (char*)d_ws;

  float2* Wt = (float2*)ws;                      // 32 KB
  float* Mdr = (float*)(ws + 32768);             // 48 KB (3 bands)
  float* xT = (float*)(ws + 131072);             // 16.78 MB (optional)
  int use_xt = (ws_size >= (size_t)131072 + (size_t)16 * 64 * 4096 * 4) ? 1 : 0;
  int n_trans = use_xt ? 1024 : 0;

  setup_k<<<n_trans + 16, NTH, 0, stream>>>(x, xT, Wt, Mdr, n_trans);
  tf_main<<<512, NTH, 0, stream>>>(x, xT, use_xt, Wt, Mdr, out);
}